// Round 1
// baseline (2772.044 us; speedup 1.0000x reference)
//
#include <hip/hip_runtime.h>
#include <climits>
#include <cstdint>

#define NV    2048
#define MAXE  344
#define HSIZE 8192
#define HMASK 8191
#define BIGK  LLONG_MAX

__device__ __forceinline__ unsigned hashk(long long k) {
  unsigned long long x = (unsigned long long)k * 0x9E3779B97F4A7C15ull;
  return (unsigned)(x >> 51) & HMASK;
}

// ---------------- init ----------------
__global__ __launch_bounds__(256) void k_init(const float* __restrict__ vf,
    const int* __restrict__ coors, int* __restrict__ cA, float* __restrict__ fA,
    int* __restrict__ nact)
{
  int i = blockIdx.x * 256 + threadIdx.x;
  if (i == 0) nact[0] = NV;
  if (i >= NV) return;
  cA[i*4+0] = coors[i*4+0];
  cA[i*4+1] = coors[i*4+1];
  cA[i*4+2] = coors[i*4+2];
  cA[i*4+3] = coors[i*4+3];
  fA[i] = vf[i];
}

// ---------------- hash ----------------
__global__ __launch_bounds__(256) void k_hclear(long long* __restrict__ hk) {
  int i = blockIdx.x * 256 + threadIdx.x;
  if (i < HSIZE) hk[i] = -1LL;
}

__global__ __launch_bounds__(256) void k_hinsert(const int* __restrict__ c,
    long long* __restrict__ hk, int* __restrict__ hv, const int* __restrict__ nactp,
    int D, int H, int Wd)
{
  int i = blockIdx.x * 256 + threadIdx.x;
  if (i >= NV || i >= *nactp) return;
  long long key = (((long long)c[i*4+0]*D + c[i*4+1])*H + c[i*4+2])*(long long)Wd + c[i*4+3];
  unsigned h = hashk(key);
  while (true) {
    unsigned long long old = atomicCAS((unsigned long long*)&hk[h], ~0ull, (unsigned long long)key);
    if (old == ~0ull) { hv[h] = i; break; }
    h = (h + 1) & HMASK;
  }
}

// ---------------- neighbor hit lists (one wave per site) ----------------
template<int K>
__global__ __launch_bounds__(256) void k_hits(const int* __restrict__ c,
    const long long* __restrict__ hk, const int* __restrict__ hv,
    const int* __restrict__ nactp, int* __restrict__ ext, int* __restrict__ cnt,
    int D, int H, int Wd)
{
  constexpr int K3 = K*K*K, R = K/2, CTR = K3/2;
  const int site = blockIdx.x * 4 + (threadIdx.x >> 6);
  const int lane = threadIdx.x & 63;
  const int nact = *nactp;
  if (site >= NV) return;
  if (site >= nact) { if (lane == 0) cnt[site] = 0; return; }
  const int b = c[site*4+0], d = c[site*4+1], hc = c[site*4+2], w = c[site*4+3];
  int base = 0;
  for (int o0 = 0; o0 < K3; o0 += 64) {
    const int o = o0 + lane;
    int j = -1;
    if (o < K3 && o != CTR) {
      const int dz = o/(K*K) - R, dy = (o/K)%K - R, dx = o%K - R;
      const int nd = d+dz, nh = hc+dy, nw = w+dx;
      if (nd >= 0 && nd < D && nh >= 0 && nh < H && nw >= 0 && nw < Wd) {
        const long long key = (((long long)b*D + nd)*H + nh)*(long long)Wd + nw;
        unsigned hs = hashk(key);
        while (true) {
          const long long kk = hk[hs];
          if (kk == -1LL) break;
          if (kk == key) { j = hv[hs]; break; }
          hs = (hs + 1) & HMASK;
        }
      }
    }
    const unsigned long long m = __ballot(j >= 0);
    if (j >= 0) {
      const int pos = __popcll(m & ((1ull << lane) - 1ull));
      ext[site * MAXE + base + pos] = (o << 12) | j;
    }
    base += __popcll(m);
  }
  if (lane == 0) cnt[site] = base;
}

// ---------------- dense center GEMM: out = f @ Wc ----------------
template<int CIN, int COUT>
__global__ __launch_bounds__(256) void k_gemm(const float* __restrict__ f,
    const float* __restrict__ Wc, float* __restrict__ out, const int* __restrict__ nactp)
{
  constexpr int TM  = 8;
  constexpr int CPT = (COUT + 255) / 256;
  constexpr int RG  = (COUT < 256) ? (256 / COUT) : 1;
  constexpr int RPT = TM / RG;
  __shared__ float as[TM * CIN];
  const int tid  = threadIdx.x;
  const int row0 = blockIdx.x * TM;
  const int nact = *nactp;
  const int cbase = (RG > 1) ? (tid % COUT) : tid;
  const int rbase = (RG > 1) ? (tid / COUT) * RPT : 0;
  if (row0 >= nact) {
    #pragma unroll
    for (int i = 0; i < RPT; ++i)
      #pragma unroll
      for (int j = 0; j < CPT; ++j) {
        int cc = cbase + j * 256;
        if (cc < COUT) out[(row0 + rbase + i) * COUT + cc] = 0.f;
      }
    return;
  }
  for (int idx = tid; idx < TM * CIN; idx += 256)
    as[idx] = f[row0 * CIN + idx];
  __syncthreads();
  float acc[RPT][CPT];
  #pragma unroll
  for (int i = 0; i < RPT; ++i)
    #pragma unroll
    for (int j = 0; j < CPT; ++j) acc[i][j] = 0.f;
  #pragma unroll 4
  for (int k = 0; k < CIN; ++k) {
    float wv[CPT];
    #pragma unroll
    for (int j = 0; j < CPT; ++j) {
      int cc = cbase + j * 256;
      wv[j] = (cc < COUT) ? Wc[k * COUT + cc] : 0.f;
    }
    #pragma unroll
    for (int i = 0; i < RPT; ++i) {
      const float av = as[(rbase + i) * CIN + k];
      #pragma unroll
      for (int j = 0; j < CPT; ++j) acc[i][j] += av * wv[j];
    }
  }
  #pragma unroll
  for (int i = 0; i < RPT; ++i)
    #pragma unroll
    for (int j = 0; j < CPT; ++j) {
      int cc = cbase + j * 256;
      if (cc < COUT) out[(row0 + rbase + i) * COUT + cc] = acc[i][j];
    }
}

// ---------------- sparse extra hits: out[i] += sum_h f[j_h] @ W[o_h] ----------------
template<int CIN, int COUT>
__global__ __launch_bounds__(256) void k_extra(const float* __restrict__ f,
    const float* __restrict__ Wall, float* __restrict__ out,
    const int* __restrict__ ext, const int* __restrict__ cnt, const int* __restrict__ nactp)
{
  const int i = blockIdx.x;
  if (i >= *nactp) return;
  const int n = cnt[i];
  if (n == 0) return;
  constexpr int CPT = (COUT + 255) / 256;
  __shared__ float fs[CIN];
  const int tid = threadIdx.x;
  float acc[CPT];
  #pragma unroll
  for (int j2 = 0; j2 < CPT; ++j2) acc[j2] = 0.f;
  for (int h = 0; h < n; ++h) {
    const int e = ext[i * MAXE + h];
    const int j = e & 0xFFF;
    const int o = e >> 12;
    __syncthreads();
    for (int idx = tid; idx < CIN; idx += 256) fs[idx] = f[j * CIN + idx];
    __syncthreads();
    const float* Wo = Wall + (size_t)o * (CIN * COUT);
    for (int k = 0; k < CIN; ++k) {
      const float fv = fs[k];
      #pragma unroll
      for (int j2 = 0; j2 < CPT; ++j2) {
        int cc = tid + j2 * 256;
        if (cc < COUT) acc[j2] += fv * Wo[k * COUT + cc];
      }
    }
  }
  #pragma unroll
  for (int j2 = 0; j2 < CPT; ++j2) {
    int cc = tid + j2 * 256;
    if (cc < COUT) out[i * COUT + cc] += acc[j2];
  }
}

// ---------------- BN stats -> scale/shift ----------------
template<int COUT>
__global__ __launch_bounds__(256) void k_bnstats(const float* __restrict__ x,
    const float* __restrict__ g, const float* __restrict__ b,
    float* __restrict__ scale, float* __restrict__ shift, const int* __restrict__ nactp)
{
  const int c = blockIdx.x;
  const int tid = threadIdx.x;
  double s1 = 0.0, s2 = 0.0;
  for (int r = tid; r < NV; r += 256) {
    const double v = (double)x[r * COUT + c];
    s1 += v; s2 += v * v;
  }
  __shared__ double r1[256], r2[256];
  r1[tid] = s1; r2[tid] = s2;
  __syncthreads();
  for (int off = 128; off > 0; off >>= 1) {
    if (tid < off) { r1[tid] += r1[tid + off]; r2[tid] += r2[tid + off]; }
    __syncthreads();
  }
  if (tid == 0) {
    const double n = (double)(*nactp);
    const double mu = r1[0] / n;
    double var = r2[0] / n - mu * mu;
    if (var < 0.0) var = 0.0;
    const double sc = (double)g[c] / sqrt(var + 1e-4);
    scale[c] = (float)sc;
    shift[c] = (float)((double)b[c] - mu * sc);
  }
}

// ---------------- BN apply + ReLU (in place) ----------------
template<int COUT>
__global__ __launch_bounds__(256) void k_bnrelu(float* __restrict__ x,
    const float* __restrict__ scale, const float* __restrict__ shift,
    const int* __restrict__ nactp)
{
  const int idx = blockIdx.x * 256 + threadIdx.x;
  if (idx >= NV * COUT) return;
  const int i = idx / COUT, c = idx % COUT;
  float v = 0.f;
  if (i < *nactp) {
    const float y = fmaf(x[idx], scale[c], shift[c]);
    v = (y > 0.f) ? y : 0.f;   // also canonicalizes -0 -> +0
  }
  x[idx] = v;
}

// ---------------- pooling ----------------
__global__ __launch_bounds__(256) void k_poolkey(const int* __restrict__ c,
    long long* __restrict__ pk, const int* __restrict__ nactp,
    int sd, int sh, int sw, int oD, int oH, int oW)
{
  const int i = blockIdx.x * 256 + threadIdx.x;
  if (i >= NV) return;
  if (i < *nactp) {
    const int b = c[i*4+0];
    const int d = c[i*4+1] / sd, h = c[i*4+2] / sh, w = c[i*4+3] / sw;
    pk[i] = (((long long)b*oD + d)*oH + h)*(long long)oW + w;
  } else pk[i] = BIGK;
}

__global__ __launch_bounds__(1024) void k_sortcompact(const long long* __restrict__ pk,
    int* __restrict__ cNew, int* __restrict__ map, int* __restrict__ nactOut,
    int D, int H, int Wd)
{
  __shared__ long long sk[NV];
  __shared__ int si[NV];
  __shared__ int sc[NV];
  __shared__ int s2[NV];
  const int tid = threadIdx.x;
  for (int e = 0; e < 2; ++e) { const int t = tid + e*1024; sk[t] = pk[t]; si[t] = t; }
  __syncthreads();
  for (int k = 2; k <= NV; k <<= 1)
    for (int j = k >> 1; j > 0; j >>= 1) {
      for (int e = 0; e < 2; ++e) {
        const int i = tid + e*1024;
        const int ixj = i ^ j;
        if (ixj > i) {
          const bool up = ((i & k) == 0);
          const long long a = sk[i], bb = sk[ixj];
          const bool sw = up ? (a > bb) : (a < bb);
          if (sw) { sk[i] = bb; sk[ixj] = a; const int t2 = si[i]; si[i] = si[ixj]; si[ixj] = t2; }
        }
      }
      __syncthreads();
    }
  for (int e = 0; e < 2; ++e) {
    const int t = tid + e*1024;
    sc[t] = (sk[t] != BIGK && (t == 0 || sk[t] != sk[t-1])) ? 1 : 0;
  }
  __syncthreads();
  for (int d2 = 1; d2 < NV; d2 <<= 1) {
    for (int e = 0; e < 2; ++e) { const int t = tid + e*1024; s2[t] = sc[t] + ((t >= d2) ? sc[t - d2] : 0); }
    __syncthreads();
    for (int e = 0; e < 2; ++e) { const int t = tid + e*1024; sc[t] = s2[t]; }
    __syncthreads();
  }
  for (int e = 0; e < 2; ++e) {
    const int t = tid + e*1024;
    const long long key = sk[t];
    if (key != BIGK) {
      const int g = sc[t] - 1;
      map[si[t]] = g;
      if (t == 0 || sk[t-1] != key) {
        const int w = (int)(key % Wd);
        long long r = key / Wd;
        const int h = (int)(r % H); r /= H;
        const int d = (int)(r % D);
        const int b = (int)(r / D);
        cNew[g*4+0] = b; cNew[g*4+1] = d; cNew[g*4+2] = h; cNew[g*4+3] = w;
      }
    }
  }
  if (tid == 0) *nactOut = sc[NV-1];
}

__global__ __launch_bounds__(256) void k_zero(float* __restrict__ x, int n) {
  const int idx = blockIdx.x * 256 + threadIdx.x;
  if (idx < n) x[idx] = 0.f;
}

template<int C>
__global__ __launch_bounds__(256) void k_pscatter(const float* __restrict__ src,
    float* __restrict__ dst, const int* __restrict__ map, const int* __restrict__ nactp)
{
  const int idx = blockIdx.x * 256 + threadIdx.x;
  const int i = idx / C;
  if (i >= *nactp) return;
  atomicMax((unsigned*)&dst[map[i] * C + (idx % C)], __float_as_uint(src[idx]));
}

// ---------------- final dense scatter ----------------
__global__ __launch_bounds__(256) void k_out(const float* __restrict__ f,
    const int* __restrict__ c, float* __restrict__ out, const int* __restrict__ nactp)
{
  const int idx = blockIdx.x * 256 + threadIdx.x;
  const int i = idx >> 9, ch = idx & 511;
  if (i >= *nactp) return;
  const int b = c[i*4+0], d = c[i*4+1], h = c[i*4+2], w = c[i*4+3];
  out[ (((b*512 + ch)*2 + d)*111 + h)*98 + w ] = f[idx];
}

// ---------------- host orchestration ----------------
template<int K, int CIN, int C>
static void run_stage(hipStream_t stream, int s,
    const float* Wa, const float* Ga, const float* Ba,
    const float* Wb, const float* Gb, const float* Bb,
    float* fX, float* fY, int* cX, int* cY,
    int D, int H, int W, int pd, int ph, int pw, int oD, int oH, int oW,
    long long* hk, int* hv, long long* pkey, int* ext, int* cnt, int* map,
    int* nact, float* scale, float* shift)
{
  constexpr int K3 = K*K*K;
  constexpr int CTR = K3/2;
  const int* na = nact + s;
  k_hclear<<<HSIZE/256, 256, 0, stream>>>(hk);
  k_hinsert<<<NV/256, 256, 0, stream>>>(cX, hk, hv, na, D, H, W);
  k_hits<K><<<NV/4, 256, 0, stream>>>(cX, hk, hv, na, ext, cnt, D, H, W);
  k_gemm<CIN, C><<<NV/8, 256, 0, stream>>>(fX, Wa + (size_t)CTR*CIN*C, fY, na);
  k_extra<CIN, C><<<NV, 256, 0, stream>>>(fX, Wa, fY, ext, cnt, na);
  k_bnstats<C><<<C, 256, 0, stream>>>(fY, Ga, Ba, scale, shift, na);
  k_bnrelu<C><<<NV*C/256, 256, 0, stream>>>(fY, scale, shift, na);
  k_gemm<C, C><<<NV/8, 256, 0, stream>>>(fY, Wb + (size_t)CTR*C*C, fX, na);
  k_extra<C, C><<<NV, 256, 0, stream>>>(fY, Wb, fX, ext, cnt, na);
  k_bnstats<C><<<C, 256, 0, stream>>>(fX, Gb, Bb, scale, shift, na);
  k_bnrelu<C><<<NV*C/256, 256, 0, stream>>>(fX, scale, shift, na);
  k_poolkey<<<NV/256, 256, 0, stream>>>(cX, pkey, na, pd, ph, pw, oD, oH, oW);
  k_sortcompact<<<1, 1024, 0, stream>>>(pkey, cY, map, nact + s + 1, oD, oH, oW);
  k_zero<<<NV*C/256, 256, 0, stream>>>(fY, NV*C);
  k_pscatter<C><<<NV*C/256, 256, 0, stream>>>(fX, fY, map, na);
}

extern "C" void kernel_launch(void* const* d_in, const int* in_sizes, int n_in,
                              void* d_out, int out_size, void* d_ws, size_t ws_size,
                              hipStream_t stream)
{
  const float* vf    = (const float*)d_in[0];
  const int*   coors = (const int*)d_in[1];
  const float *Wl[10], *Gl[10], *Bl[10];
  for (int i = 0; i < 10; ++i) {
    Wl[i] = (const float*)d_in[3 + 3*i];
    Gl[i] = (const float*)d_in[4 + 3*i];
    Bl[i] = (const float*)d_in[5 + 3*i];
  }

  char* p = (char*)d_ws;
  auto alloc = [&](size_t bytes) { char* q = p; p += (bytes + 255) & ~(size_t)255; return q; };
  float*     fB    = (float*)    alloc((size_t)NV*512*4);
  long long* hk    = (long long*)alloc((size_t)HSIZE*8);
  long long* pkey  = (long long*)alloc((size_t)NV*8);
  int*       hv    = (int*)      alloc((size_t)HSIZE*4);
  int*       cA    = (int*)      alloc((size_t)NV*4*4);
  int*       cB    = (int*)      alloc((size_t)NV*4*4);
  int*       ext   = (int*)      alloc((size_t)NV*MAXE*4);
  int*       cnt   = (int*)      alloc((size_t)NV*4);
  int*       map   = (int*)      alloc((size_t)NV*4);
  int*       nact  = (int*)      alloc(8*4);
  float*     scale = (float*)    alloc(512*4);
  float*     shift = (float*)    alloc(512*4);

  float* fA = (float*)d_out;   // 4 MB scratch aliased into d_out; dead before final memset

  k_init<<<NV/256, 256, 0, stream>>>(vf, coors, cA, fA, nact);

  run_stage<7, 1, 64>  (stream, 0, Wl[0],Gl[0],Bl[0], Wl[1],Gl[1],Bl[1],
    fA, fB, cA, cB, 216, 7992, 7056, 3, 3, 3, 72, 2664, 2352,
    hk, hv, pkey, ext, cnt, map, nact, scale, shift);
  run_stage<7, 64, 128>(stream, 1, Wl[2],Gl[2],Bl[2], Wl[3],Gl[3],Bl[3],
    fB, fA, cB, cA, 72, 2664, 2352, 3, 3, 3, 24, 888, 784,
    hk, hv, pkey, ext, cnt, map, nact, scale, shift);
  run_stage<5, 128, 256>(stream, 2, Wl[4],Gl[4],Bl[4], Wl[5],Gl[5],Bl[5],
    fA, fB, cA, cB, 24, 888, 784, 3, 2, 2, 8, 444, 392,
    hk, hv, pkey, ext, cnt, map, nact, scale, shift);
  run_stage<3, 256, 384>(stream, 3, Wl[6],Gl[6],Bl[6], Wl[7],Gl[7],Bl[7],
    fB, fA, cB, cA, 8, 444, 392, 2, 2, 2, 4, 222, 196,
    hk, hv, pkey, ext, cnt, map, nact, scale, shift);
  run_stage<3, 384, 512>(stream, 4, Wl[8],Gl[8],Bl[8], Wl[9],Gl[9],Bl[9],
    fA, fB, cA, cB, 4, 222, 196, 2, 2, 2, 2, 111, 98,
    hk, hv, pkey, ext, cnt, map, nact, scale, shift);

  hipMemsetAsync(d_out, 0, (size_t)out_size * sizeof(float), stream);
  k_out<<<NV*512/256, 256, 0, stream>>>(fB, cB, (float*)d_out, nact + 5);
}

// Round 2
// 1537.414 us; speedup vs baseline: 1.8031x; 1.8031x over previous
//
#include <hip/hip_runtime.h>
#include <climits>
#include <cstdint>

#define NV    2048
#define MAXE  344
#define HSIZE 8192
#define HMASK 8191
#define BIGK  LLONG_MAX
#define K3MAX 343

__device__ __forceinline__ unsigned hashk(long long k) {
  unsigned long long x = (unsigned long long)k * 0x9E3779B97F4A7C15ull;
  return (unsigned)(x >> 51) & HMASK;
}

// ---------------- init ----------------
__global__ __launch_bounds__(256) void k_init(const float* __restrict__ vf,
    const int* __restrict__ coors, int* __restrict__ cA, float* __restrict__ fA,
    int* __restrict__ nact)
{
  int i = blockIdx.x * 256 + threadIdx.x;
  if (i == 0) nact[0] = NV;
  if (i >= NV) return;
  cA[i*4+0] = coors[i*4+0];
  cA[i*4+1] = coors[i*4+1];
  cA[i*4+2] = coors[i*4+2];
  cA[i*4+3] = coors[i*4+3];
  fA[i] = vf[i];
}

// ---------------- hash ----------------
__global__ __launch_bounds__(256) void k_hclear(long long* __restrict__ hk,
    int* __restrict__ ocnt)
{
  int i = blockIdx.x * 256 + threadIdx.x;
  if (i < HSIZE) hk[i] = -1LL;
  if (i < K3MAX) ocnt[i] = 0;
}

__global__ __launch_bounds__(256) void k_hinsert(const int* __restrict__ c,
    long long* __restrict__ hk, int* __restrict__ hv, const int* __restrict__ nactp,
    int D, int H, int Wd)
{
  int i = blockIdx.x * 256 + threadIdx.x;
  if (i >= NV || i >= *nactp) return;
  long long key = (((long long)c[i*4+0]*D + c[i*4+1])*H + c[i*4+2])*(long long)Wd + c[i*4+3];
  unsigned h = hashk(key);
  while (true) {
    unsigned long long old = atomicCAS((unsigned long long*)&hk[h], ~0ull, (unsigned long long)key);
    if (old == ~0ull) { hv[h] = i; break; }
    h = (h + 1) & HMASK;
  }
}

// ---------------- neighbor hit lists (one wave per site), grouped by offset ----------------
template<int K, int MAXP>
__global__ __launch_bounds__(256) void k_hits(const int* __restrict__ c,
    const long long* __restrict__ hk, const int* __restrict__ hv,
    const int* __restrict__ nactp, int* __restrict__ pslot, int* __restrict__ cnt,
    int* __restrict__ ocnt, int* __restrict__ olist,
    int D, int H, int Wd)
{
  constexpr int K3 = K*K*K, R = K/2, CTR = K3/2;
  const int site = blockIdx.x * 4 + (threadIdx.x >> 6);
  const int lane = threadIdx.x & 63;
  const int nact = *nactp;
  if (site >= NV) return;
  if (site >= nact) { if (lane == 0) cnt[site] = 0; return; }
  const int b = c[site*4+0], d = c[site*4+1], hc = c[site*4+2], w = c[site*4+3];
  int base = 0;
  for (int o0 = 0; o0 < K3; o0 += 64) {
    const int o = o0 + lane;
    int j = -1;
    if (o < K3 && o != CTR) {
      const int dz = o/(K*K) - R, dy = (o/K)%K - R, dx = o%K - R;
      const int nd = d+dz, nh = hc+dy, nw = w+dx;
      if (nd >= 0 && nd < D && nh >= 0 && nh < H && nw >= 0 && nw < Wd) {
        const long long key = (((long long)b*D + nd)*H + nh)*(long long)Wd + nw;
        unsigned hs = hashk(key);
        while (true) {
          const long long kk = hk[hs];
          if (kk == -1LL) break;
          if (kk == key) { j = hv[hs]; break; }
          hs = (hs + 1) & HMASK;
        }
      }
    }
    const unsigned long long m = __ballot(j >= 0);
    if (j >= 0) {
      const int pos = __popcll(m & ((1ull << lane) - 1ull));
      const int p = atomicAdd(&ocnt[o], 1);
      int slot = -1;
      if (p < MAXP) { olist[o * MAXP + p] = (site << 12) | j; slot = o * MAXP + p; }
      pslot[site * MAXE + base + pos] = slot;
    }
    base += __popcll(m);
  }
  if (lane == 0) cnt[site] = base;
}

// ---------------- dense center GEMM: out = f @ Wc ----------------
template<int CIN, int COUT>
__global__ __launch_bounds__(256) void k_gemm(const float* __restrict__ f,
    const float* __restrict__ Wc, float* __restrict__ out, const int* __restrict__ nactp)
{
  constexpr int TM  = 8;
  constexpr int CPT = (COUT + 255) / 256;
  constexpr int RG  = (COUT < 256) ? (256 / COUT) : 1;
  constexpr int RPT = TM / RG;
  __shared__ float as[TM * CIN];
  const int tid  = threadIdx.x;
  const int row0 = blockIdx.x * TM;
  const int nact = *nactp;
  const int cbase = (RG > 1) ? (tid % COUT) : tid;
  const int rbase = (RG > 1) ? (tid / COUT) * RPT : 0;
  if (row0 >= nact) {
    #pragma unroll
    for (int i = 0; i < RPT; ++i)
      #pragma unroll
      for (int j = 0; j < CPT; ++j) {
        int cc = cbase + j * 256;
        if (cc < COUT) out[(row0 + rbase + i) * COUT + cc] = 0.f;
      }
    return;
  }
  for (int idx = tid; idx < TM * CIN; idx += 256)
    as[idx] = f[row0 * CIN + idx];
  __syncthreads();
  float acc[RPT][CPT];
  #pragma unroll
  for (int i = 0; i < RPT; ++i)
    #pragma unroll
    for (int j = 0; j < CPT; ++j) acc[i][j] = 0.f;
  #pragma unroll 4
  for (int k = 0; k < CIN; ++k) {
    float wv[CPT];
    #pragma unroll
    for (int j = 0; j < CPT; ++j) {
      int cc = cbase + j * 256;
      wv[j] = (cc < COUT) ? Wc[k * COUT + cc] : 0.f;
    }
    #pragma unroll
    for (int i = 0; i < RPT; ++i) {
      const float av = as[(rbase + i) * CIN + k];
      #pragma unroll
      for (int j = 0; j < CPT; ++j) acc[i][j] += av * wv[j];
    }
  }
  #pragma unroll
  for (int i = 0; i < RPT; ++i)
    #pragma unroll
    for (int j = 0; j < CPT; ++j) {
      int cc = cbase + j * 256;
      if (cc < COUT) out[(row0 + rbase + i) * COUT + cc] = acc[i][j];
    }
}

// ---------------- phase 1: per-offset partial GEMM  P[slot] = f[j] @ W[o] ----------------
template<int CIN, int COUT, int MAXP>
__global__ __launch_bounds__(256) void k_pgemm(const float* __restrict__ f,
    const float* __restrict__ Wall, float* __restrict__ P,
    const int* __restrict__ ocnt, const int* __restrict__ olist)
{
  constexpr int NCH = (COUT + 255) / 256;
  constexpr int HB = 8;
  const int o  = blockIdx.x / NCH;
  const int ch = blockIdx.x % NCH;
  int m = ocnt[o];
  if (m == 0) return;
  if (m > MAXP) m = MAXP;
  const int tid = threadIdx.x;
  const int c = ch * 256 + tid;
  __shared__ float fs[HB][CIN];
  const float* Wo = Wall + (size_t)o * (CIN * COUT);
  for (int p0 = 0; p0 < m; p0 += HB) {
    const int hb = min(HB, m - p0);
    __syncthreads();
    for (int idx = tid; idx < hb * CIN; idx += 256) {
      const int h = idx / CIN, k = idx % CIN;
      const int j = olist[o * MAXP + p0 + h] & 0xFFF;
      fs[h][k] = f[j * CIN + k];
    }
    __syncthreads();
    if (c < COUT) {
      float acc[HB];
      #pragma unroll
      for (int h = 0; h < HB; ++h) acc[h] = 0.f;
      for (int k = 0; k < CIN; ++k) {
        const float wv = Wo[k * COUT + c];
        #pragma unroll
        for (int h = 0; h < HB; ++h) acc[h] += fs[h][k] * wv;
      }
      for (int h = 0; h < hb; ++h)
        P[(size_t)(o * MAXP + p0 + h) * COUT + c] = acc[h];
    }
  }
}

// ---------------- phase 2: per-site deterministic sum of partials ----------------
template<int COUT>
__global__ __launch_bounds__(256) void k_psum(float* __restrict__ out,
    const float* __restrict__ P, const int* __restrict__ pslot,
    const int* __restrict__ cnt, const int* __restrict__ nactp)
{
  const int idx = blockIdx.x * 256 + threadIdx.x;
  const int i = idx / COUT;
  if (i >= *nactp) return;
  const int n = cnt[i];
  if (n == 0) return;
  const int cc = idx - i * COUT;
  float acc = 0.f;
  for (int h = 0; h < n; ++h) {
    const int slot = pslot[i * MAXE + h];
    if (slot >= 0) acc += P[(size_t)slot * COUT + cc];
  }
  out[idx] += acc;
}

// ---------------- BN stats -> scale/shift ----------------
template<int COUT>
__global__ __launch_bounds__(256) void k_bnstats(const float* __restrict__ x,
    const float* __restrict__ g, const float* __restrict__ b,
    float* __restrict__ scale, float* __restrict__ shift, const int* __restrict__ nactp)
{
  const int c = blockIdx.x;
  const int tid = threadIdx.x;
  double s1 = 0.0, s2 = 0.0;
  for (int r = tid; r < NV; r += 256) {
    const double v = (double)x[r * COUT + c];
    s1 += v; s2 += v * v;
  }
  __shared__ double r1[256], r2[256];
  r1[tid] = s1; r2[tid] = s2;
  __syncthreads();
  for (int off = 128; off > 0; off >>= 1) {
    if (tid < off) { r1[tid] += r1[tid + off]; r2[tid] += r2[tid + off]; }
    __syncthreads();
  }
  if (tid == 0) {
    const double n = (double)(*nactp);
    const double mu = r1[0] / n;
    double var = r2[0] / n - mu * mu;
    if (var < 0.0) var = 0.0;
    const double sc = (double)g[c] / sqrt(var + 1e-4);
    scale[c] = (float)sc;
    shift[c] = (float)((double)b[c] - mu * sc);
  }
}

// ---------------- BN apply + ReLU (in place) ----------------
template<int COUT>
__global__ __launch_bounds__(256) void k_bnrelu(float* __restrict__ x,
    const float* __restrict__ scale, const float* __restrict__ shift,
    const int* __restrict__ nactp)
{
  const int idx = blockIdx.x * 256 + threadIdx.x;
  if (idx >= NV * COUT) return;
  const int i = idx / COUT, c = idx % COUT;
  float v = 0.f;
  if (i < *nactp) {
    const float y = fmaf(x[idx], scale[c], shift[c]);
    v = (y > 0.f) ? y : 0.f;   // also canonicalizes -0 -> +0
  }
  x[idx] = v;
}

// ---------------- pooling ----------------
__global__ __launch_bounds__(256) void k_poolkey(const int* __restrict__ c,
    long long* __restrict__ pk, const int* __restrict__ nactp,
    int sd, int sh, int sw, int oD, int oH, int oW)
{
  const int i = blockIdx.x * 256 + threadIdx.x;
  if (i >= NV) return;
  if (i < *nactp) {
    const int b = c[i*4+0];
    const int d = c[i*4+1] / sd, h = c[i*4+2] / sh, w = c[i*4+3] / sw;
    pk[i] = (((long long)b*oD + d)*oH + h)*(long long)oW + w;
  } else pk[i] = BIGK;
}

__global__ __launch_bounds__(1024) void k_sortcompact(const long long* __restrict__ pk,
    int* __restrict__ cNew, int* __restrict__ map, int* __restrict__ nactOut,
    int D, int H, int Wd)
{
  __shared__ long long sk[NV];
  __shared__ int si[NV];
  __shared__ int sc[NV];
  __shared__ int s2[NV];
  const int tid = threadIdx.x;
  for (int e = 0; e < 2; ++e) { const int t = tid + e*1024; sk[t] = pk[t]; si[t] = t; }
  __syncthreads();
  for (int k = 2; k <= NV; k <<= 1)
    for (int j = k >> 1; j > 0; j >>= 1) {
      for (int e = 0; e < 2; ++e) {
        const int i = tid + e*1024;
        const int ixj = i ^ j;
        if (ixj > i) {
          const bool up = ((i & k) == 0);
          const long long a = sk[i], bb = sk[ixj];
          const bool sw = up ? (a > bb) : (a < bb);
          if (sw) { sk[i] = bb; sk[ixj] = a; const int t2 = si[i]; si[i] = si[ixj]; si[ixj] = t2; }
        }
      }
      __syncthreads();
    }
  for (int e = 0; e < 2; ++e) {
    const int t = tid + e*1024;
    sc[t] = (sk[t] != BIGK && (t == 0 || sk[t] != sk[t-1])) ? 1 : 0;
  }
  __syncthreads();
  for (int d2 = 1; d2 < NV; d2 <<= 1) {
    for (int e = 0; e < 2; ++e) { const int t = tid + e*1024; s2[t] = sc[t] + ((t >= d2) ? sc[t - d2] : 0); }
    __syncthreads();
    for (int e = 0; e < 2; ++e) { const int t = tid + e*1024; sc[t] = s2[t]; }
    __syncthreads();
  }
  for (int e = 0; e < 2; ++e) {
    const int t = tid + e*1024;
    const long long key = sk[t];
    if (key != BIGK) {
      const int g = sc[t] - 1;
      map[si[t]] = g;
      if (t == 0 || sk[t-1] != key) {
        const int w = (int)(key % Wd);
        long long r = key / Wd;
        const int h = (int)(r % H); r /= H;
        const int d = (int)(r % D);
        const int b = (int)(r / D);
        cNew[g*4+0] = b; cNew[g*4+1] = d; cNew[g*4+2] = h; cNew[g*4+3] = w;
      }
    }
  }
  if (tid == 0) *nactOut = sc[NV-1];
}

__global__ __launch_bounds__(256) void k_zero(float* __restrict__ x, int n) {
  const int idx = blockIdx.x * 256 + threadIdx.x;
  if (idx < n) x[idx] = 0.f;
}

template<int C>
__global__ __launch_bounds__(256) void k_pscatter(const float* __restrict__ src,
    float* __restrict__ dst, const int* __restrict__ map, const int* __restrict__ nactp)
{
  const int idx = blockIdx.x * 256 + threadIdx.x;
  const int i = idx / C;
  if (i >= *nactp) return;
  atomicMax((unsigned*)&dst[map[i] * C + (idx % C)], __float_as_uint(src[idx]));
}

// ---------------- final dense scatter ----------------
__global__ __launch_bounds__(256) void k_out(const float* __restrict__ f,
    const int* __restrict__ c, float* __restrict__ out, const int* __restrict__ nactp)
{
  const int idx = blockIdx.x * 256 + threadIdx.x;
  const int i = idx >> 9, ch = idx & 511;
  if (i >= *nactp) return;
  const int b = c[i*4+0], d = c[i*4+1], h = c[i*4+2], w = c[i*4+3];
  out[ (((b*512 + ch)*2 + d)*111 + h)*98 + w ] = f[idx];
}

// ---------------- host orchestration ----------------
template<int K, int CIN, int C, int MAXP>
static void run_stage(hipStream_t stream, int s,
    const float* Wa, const float* Ga, const float* Ba,
    const float* Wb, const float* Gb, const float* Bb,
    float* fX, float* fY, int* cX, int* cY,
    int D, int H, int W, int pd, int ph, int pw, int oD, int oH, int oW,
    long long* hk, int* hv, long long* pkey, int* pslot, int* cnt, int* map,
    int* nact, float* scale, float* shift,
    int* ocnt, int* olist, float* P)
{
  constexpr int K3 = K*K*K;
  constexpr int CTR = K3/2;
  constexpr int NCH = (C + 255) / 256;
  const int* na = nact + s;
  k_hclear<<<HSIZE/256, 256, 0, stream>>>(hk, ocnt);
  k_hinsert<<<NV/256, 256, 0, stream>>>(cX, hk, hv, na, D, H, W);
  k_hits<K, MAXP><<<NV/4, 256, 0, stream>>>(cX, hk, hv, na, pslot, cnt, ocnt, olist, D, H, W);

  k_gemm<CIN, C><<<NV/8, 256, 0, stream>>>(fX, Wa + (size_t)CTR*CIN*C, fY, na);
  k_pgemm<CIN, C, MAXP><<<K3*NCH, 256, 0, stream>>>(fX, Wa, P, ocnt, olist);
  k_psum<C><<<NV*C/256, 256, 0, stream>>>(fY, P, pslot, cnt, na);
  k_bnstats<C><<<C, 256, 0, stream>>>(fY, Ga, Ba, scale, shift, na);
  k_bnrelu<C><<<NV*C/256, 256, 0, stream>>>(fY, scale, shift, na);

  k_gemm<C, C><<<NV/8, 256, 0, stream>>>(fY, Wb + (size_t)CTR*C*C, fX, na);
  k_pgemm<C, C, MAXP><<<K3*NCH, 256, 0, stream>>>(fY, Wb, P, ocnt, olist);
  k_psum<C><<<NV*C/256, 256, 0, stream>>>(fX, P, pslot, cnt, na);
  k_bnstats<C><<<C, 256, 0, stream>>>(fX, Gb, Bb, scale, shift, na);
  k_bnrelu<C><<<NV*C/256, 256, 0, stream>>>(fX, scale, shift, na);

  k_poolkey<<<NV/256, 256, 0, stream>>>(cX, pkey, na, pd, ph, pw, oD, oH, oW);
  k_sortcompact<<<1, 1024, 0, stream>>>(pkey, cY, map, nact + s + 1, oD, oH, oW);
  k_zero<<<NV*C/256, 256, 0, stream>>>(fY, NV*C);
  k_pscatter<C><<<NV*C/256, 256, 0, stream>>>(fX, fY, map, na);
}

extern "C" void kernel_launch(void* const* d_in, const int* in_sizes, int n_in,
                              void* d_out, int out_size, void* d_ws, size_t ws_size,
                              hipStream_t stream)
{
  const float* vf    = (const float*)d_in[0];
  const int*   coors = (const int*)d_in[1];
  const float *Wl[10], *Gl[10], *Bl[10];
  for (int i = 0; i < 10; ++i) {
    Wl[i] = (const float*)d_in[3 + 3*i];
    Gl[i] = (const float*)d_in[4 + 3*i];
    Bl[i] = (const float*)d_in[5 + 3*i];
  }

  char* p = (char*)d_ws;
  auto alloc = [&](size_t bytes) { char* q = p; p += (bytes + 255) & ~(size_t)255; return q; };
  float*     fB    = (float*)    alloc((size_t)NV*512*4);
  long long* hk    = (long long*)alloc((size_t)HSIZE*8);
  long long* pkey  = (long long*)alloc((size_t)NV*8);
  int*       hv    = (int*)      alloc((size_t)HSIZE*4);
  int*       cA    = (int*)      alloc((size_t)NV*4*4);
  int*       cB    = (int*)      alloc((size_t)NV*4*4);
  int*       pslot = (int*)      alloc((size_t)NV*MAXE*4);
  int*       cnt   = (int*)      alloc((size_t)NV*4);
  int*       map   = (int*)      alloc((size_t)NV*4);
  int*       nact  = (int*)      alloc(8*4);
  float*     scale = (float*)    alloc(512*4);
  float*     shift = (float*)    alloc(512*4);
  int*       ocnt  = (int*)      alloc((size_t)K3MAX*4);

  // scratch aliased into d_out (89 MB); all dead before the final memset
  float* fA    = (float*)d_out;                                   // 4 MB
  float* P     = (float*)((char*)d_out + (size_t)4*1024*1024);    // up to ~16.4 MB
  int*   olist = (int*)  ((char*)d_out + (size_t)24*1024*1024);   // 343*256*4 = 351 KB

  k_init<<<NV/256, 256, 0, stream>>>(vf, coors, cA, fA, nact);

  run_stage<7, 1, 64, 64>  (stream, 0, Wl[0],Gl[0],Bl[0], Wl[1],Gl[1],Bl[1],
    fA, fB, cA, cB, 216, 7992, 7056, 3, 3, 3, 72, 2664, 2352,
    hk, hv, pkey, pslot, cnt, map, nact, scale, shift, ocnt, olist, P);
  run_stage<7, 64, 128, 64>(stream, 1, Wl[2],Gl[2],Bl[2], Wl[3],Gl[3],Bl[3],
    fB, fA, cB, cA, 72, 2664, 2352, 3, 3, 3, 24, 888, 784,
    hk, hv, pkey, pslot, cnt, map, nact, scale, shift, ocnt, olist, P);
  run_stage<5, 128, 256, 128>(stream, 2, Wl[4],Gl[4],Bl[4], Wl[5],Gl[5],Bl[5],
    fA, fB, cA, cB, 24, 888, 784, 3, 2, 2, 8, 444, 392,
    hk, hv, pkey, pslot, cnt, map, nact, scale, shift, ocnt, olist, P);
  run_stage<3, 256, 384, 256>(stream, 3, Wl[6],Gl[6],Bl[6], Wl[7],Gl[7],Bl[7],
    fB, fA, cB, cA, 8, 444, 392, 2, 2, 2, 4, 222, 196,
    hk, hv, pkey, pslot, cnt, map, nact, scale, shift, ocnt, olist, P);
  run_stage<3, 384, 512, 256>(stream, 4, Wl[8],Gl[8],Bl[8], Wl[9],Gl[9],Bl[9],
    fA, fB, cA, cB, 4, 222, 196, 2, 2, 2, 2, 111, 98,
    hk, hv, pkey, pslot, cnt, map, nact, scale, shift, ocnt, olist, P);

  hipMemsetAsync(d_out, 0, (size_t)out_size * sizeof(float), stream);
  k_out<<<NV*512/256, 256, 0, stream>>>(fB, cB, (float*)d_out, nact + 5);
}

// Round 3
// 995.251 us; speedup vs baseline: 2.7853x; 1.5448x over previous
//
#include <hip/hip_runtime.h>
#include <climits>
#include <cstdint>

#define NV    2048
#define MAXE  344
#define HSIZE 8192
#define HMASK 8191
#define BIGK  LLONG_MAX
#define K3MAX 343
#define MAXP  256

__device__ __forceinline__ unsigned hashk(long long k) {
  unsigned long long x = (unsigned long long)k * 0x9E3779B97F4A7C15ull;
  return (unsigned)(x >> 51) & HMASK;
}

// ---------------- init ----------------
__global__ __launch_bounds__(256) void k_init(const float* __restrict__ vf,
    const int* __restrict__ coors, int* __restrict__ cA, float* __restrict__ fA,
    int* __restrict__ nact)
{
  int i = blockIdx.x * 256 + threadIdx.x;
  if (i == 0) nact[0] = NV;
  if (i >= NV) return;
  cA[i*4+0] = coors[i*4+0];
  cA[i*4+1] = coors[i*4+1];
  cA[i*4+2] = coors[i*4+2];
  cA[i*4+3] = coors[i*4+3];
  fA[i] = vf[i];
}

// ---------------- hash ----------------
__global__ __launch_bounds__(256) void k_hclear(long long* __restrict__ hk,
    int* __restrict__ ocnt)
{
  int i = blockIdx.x * 256 + threadIdx.x;
  if (i < HSIZE) hk[i] = -1LL;
  if (i < K3MAX) ocnt[i] = 0;
}

__global__ __launch_bounds__(256) void k_hinsert(const int* __restrict__ c,
    long long* __restrict__ hk, int* __restrict__ hv, const int* __restrict__ nactp,
    int D, int H, int Wd)
{
  int i = blockIdx.x * 256 + threadIdx.x;
  if (i >= NV || i >= *nactp) return;
  long long key = (((long long)c[i*4+0]*D + c[i*4+1])*H + c[i*4+2])*(long long)Wd + c[i*4+3];
  unsigned h = hashk(key);
  while (true) {
    unsigned long long old = atomicCAS((unsigned long long*)&hk[h], ~0ull, (unsigned long long)key);
    if (old == ~0ull) { hv[h] = i; break; }
    h = (h + 1) & HMASK;
  }
}

// ---------------- neighbor hit lists (one wave per site), grouped by offset ----------------
template<int K>
__global__ __launch_bounds__(256) void k_hits(const int* __restrict__ c,
    const long long* __restrict__ hk, const int* __restrict__ hv,
    const int* __restrict__ nactp, int* __restrict__ pslot, int* __restrict__ cnt,
    int* __restrict__ ocnt, int* __restrict__ olist,
    int D, int H, int Wd)
{
  constexpr int K3 = K*K*K, R = K/2, CTR = K3/2;
  const int site = blockIdx.x * 4 + (threadIdx.x >> 6);
  const int lane = threadIdx.x & 63;
  const int nact = *nactp;
  if (site >= NV) return;
  if (site >= nact) { if (lane == 0) cnt[site] = 0; return; }
  const int b = c[site*4+0], d = c[site*4+1], hc = c[site*4+2], w = c[site*4+3];
  int base = 0;
  for (int o0 = 0; o0 < K3; o0 += 64) {
    const int o = o0 + lane;
    int j = -1;
    if (o < K3 && o != CTR) {
      const int dz = o/(K*K) - R, dy = (o/K)%K - R, dx = o%K - R;
      const int nd = d+dz, nh = hc+dy, nw = w+dx;
      if (nd >= 0 && nd < D && nh >= 0 && nh < H && nw >= 0 && nw < Wd) {
        const long long key = (((long long)b*D + nd)*H + nh)*(long long)Wd + nw;
        unsigned hs = hashk(key);
        while (true) {
          const long long kk = hk[hs];
          if (kk == -1LL) break;
          if (kk == key) { j = hv[hs]; break; }
          hs = (hs + 1) & HMASK;
        }
      }
    }
    const unsigned long long m = __ballot(j >= 0);
    if (j >= 0) {
      const int pos = __popcll(m & ((1ull << lane) - 1ull));
      const int p = atomicAdd(&ocnt[o], 1);
      int tag = -1;
      if (p < MAXP) { olist[o * MAXP + p] = (site << 12) | j; tag = (o << 8) | p; }
      pslot[site * MAXE + base + pos] = tag;
    }
    base += __popcll(m);
  }
  if (lane == 0) cnt[site] = base;
}

// ---------------- exclusive scan of per-offset hit counts -> compact slot bases ----------------
__global__ __launch_bounds__(512) void k_oscan(const int* __restrict__ ocnt,
    int* __restrict__ obase)
{
  __shared__ int s[512];
  const int t = threadIdx.x;
  const int v = (t < K3MAX) ? min(ocnt[t], MAXP) : 0;
  s[t] = v;
  __syncthreads();
  for (int d = 1; d < 512; d <<= 1) {
    const int x = (t >= d) ? s[t - d] : 0;
    __syncthreads();
    s[t] += x;
    __syncthreads();
  }
  if (t < K3MAX) obase[t] = s[t] - v;
}

// ---------------- dense center GEMM: out = f @ Wc ----------------
template<int CIN, int COUT>
__global__ __launch_bounds__(256) void k_gemm(const float* __restrict__ f,
    const float* __restrict__ Wc, float* __restrict__ out, const int* __restrict__ nactp)
{
  constexpr int TM  = 8;
  constexpr int CPT = (COUT + 255) / 256;
  constexpr int RG  = (COUT < 256) ? (256 / COUT) : 1;
  constexpr int RPT = TM / RG;
  __shared__ float as[TM * CIN];
  const int tid  = threadIdx.x;
  const int row0 = blockIdx.x * TM;
  const int nact = *nactp;
  const int cbase = (RG > 1) ? (tid % COUT) : tid;
  const int rbase = (RG > 1) ? (tid / COUT) * RPT : 0;
  if (row0 >= nact) {
    #pragma unroll
    for (int i = 0; i < RPT; ++i)
      #pragma unroll
      for (int j = 0; j < CPT; ++j) {
        int cc = cbase + j * 256;
        if (cc < COUT) out[(row0 + rbase + i) * COUT + cc] = 0.f;
      }
    return;
  }
  for (int idx = tid; idx < TM * CIN; idx += 256)
    as[idx] = f[row0 * CIN + idx];
  __syncthreads();
  float acc[RPT][CPT];
  #pragma unroll
  for (int i = 0; i < RPT; ++i)
    #pragma unroll
    for (int j = 0; j < CPT; ++j) acc[i][j] = 0.f;
  #pragma unroll 4
  for (int k = 0; k < CIN; ++k) {
    float wv[CPT];
    #pragma unroll
    for (int j = 0; j < CPT; ++j) {
      int cc = cbase + j * 256;
      wv[j] = (cc < COUT) ? Wc[k * COUT + cc] : 0.f;
    }
    #pragma unroll
    for (int i = 0; i < RPT; ++i) {
      const float av = as[(rbase + i) * CIN + k];
      #pragma unroll
      for (int j = 0; j < CPT; ++j) acc[i][j] += av * wv[j];
    }
  }
  #pragma unroll
  for (int i = 0; i < RPT; ++i)
    #pragma unroll
    for (int j = 0; j < CPT; ++j) {
      int cc = cbase + j * 256;
      if (cc < COUT) out[(row0 + rbase + i) * COUT + cc] = acc[i][j];
    }
}

// ---------------- phase 1: per-(offset, k-slice, col-chunk) partial GEMM ----------------
// P[(slot*KS + ks)*COUT + c] = sum_{k in slice ks} f[j][k] * W[o][k][c]
template<int CIN, int COUT>
__global__ __launch_bounds__(256) void k_pgemm(const float* __restrict__ f,
    const float* __restrict__ Wall, float* __restrict__ P,
    const int* __restrict__ ocnt, const int* __restrict__ obase,
    const int* __restrict__ olist)
{
  constexpr int NCH = (COUT + 255) / 256;
  constexpr int KB  = 64;
  constexpr int KS  = (CIN + KB - 1) / KB;
  constexpr int HB  = 8;
  const int o   = blockIdx.x / (NCH * KS);
  const int rem = blockIdx.x % (NCH * KS);
  const int ks  = rem / NCH;
  const int ch  = rem % NCH;
  int m = ocnt[o];
  if (m == 0) return;
  if (m > MAXP) m = MAXP;
  const int sbase = obase[o];
  const int k0 = ks * KB;
  const int kb = (CIN - k0 < KB) ? (CIN - k0) : KB;
  const int tid = threadIdx.x;
  const int c = ch * 256 + tid;
  __shared__ float fs[HB][KB];
  const float* Wo = Wall + (size_t)o * (CIN * COUT);
  for (int p0 = 0; p0 < m; p0 += HB) {
    const int hb = min(HB, m - p0);
    __syncthreads();
    for (int idx = tid; idx < hb * KB; idx += 256) {
      const int h = idx / KB, k = idx % KB;
      const int j = olist[o * MAXP + p0 + h] & 0xFFF;
      fs[h][k] = (k < kb) ? f[j * CIN + k0 + k] : 0.f;
    }
    __syncthreads();
    if (c < COUT) {
      float acc[HB];
      #pragma unroll
      for (int h = 0; h < HB; ++h) acc[h] = 0.f;
      #pragma unroll 4
      for (int k = 0; k < kb; ++k) {
        const float wv = Wo[(k0 + k) * COUT + c];
        #pragma unroll
        for (int h = 0; h < HB; ++h) acc[h] += fs[h][k] * wv;
      }
      for (int h = 0; h < hb; ++h)
        P[((size_t)(sbase + p0 + h) * KS + ks) * COUT + c] = acc[h];
    }
  }
}

// ---------------- phase 2: per-site deterministic sum of partials ----------------
template<int COUT, int KS>
__global__ __launch_bounds__(256) void k_psum(float* __restrict__ out,
    const float* __restrict__ P, const int* __restrict__ pslot,
    const int* __restrict__ obase, const int* __restrict__ cnt,
    const int* __restrict__ nactp)
{
  const int idx = blockIdx.x * 256 + threadIdx.x;
  const int i = idx / COUT;
  if (i >= *nactp) return;
  const int n = cnt[i];
  if (n == 0) return;
  const int cc = idx - i * COUT;
  float acc = 0.f;
  for (int h = 0; h < n; ++h) {
    const int e = pslot[i * MAXE + h];
    if (e < 0) continue;
    const int slot = obase[e >> 8] + (e & 0xFF);
    #pragma unroll
    for (int ks = 0; ks < KS; ++ks)
      acc += P[((size_t)slot * KS + ks) * COUT + cc];
  }
  out[idx] += acc;
}

// ---------------- BN stats -> scale/shift ----------------
template<int COUT>
__global__ __launch_bounds__(256) void k_bnstats(const float* __restrict__ x,
    const float* __restrict__ g, const float* __restrict__ b,
    float* __restrict__ scale, float* __restrict__ shift, const int* __restrict__ nactp)
{
  const int c = blockIdx.x;
  const int tid = threadIdx.x;
  double s1 = 0.0, s2 = 0.0;
  for (int r = tid; r < NV; r += 256) {
    const double v = (double)x[r * COUT + c];
    s1 += v; s2 += v * v;
  }
  __shared__ double r1[256], r2[256];
  r1[tid] = s1; r2[tid] = s2;
  __syncthreads();
  for (int off = 128; off > 0; off >>= 1) {
    if (tid < off) { r1[tid] += r1[tid + off]; r2[tid] += r2[tid + off]; }
    __syncthreads();
  }
  if (tid == 0) {
    const double n = (double)(*nactp);
    const double mu = r1[0] / n;
    double var = r2[0] / n - mu * mu;
    if (var < 0.0) var = 0.0;
    const double sc = (double)g[c] / sqrt(var + 1e-4);
    scale[c] = (float)sc;
    shift[c] = (float)((double)b[c] - mu * sc);
  }
}

// ---------------- BN apply + ReLU (in place) ----------------
template<int COUT>
__global__ __launch_bounds__(256) void k_bnrelu(float* __restrict__ x,
    const float* __restrict__ scale, const float* __restrict__ shift,
    const int* __restrict__ nactp)
{
  const int idx = blockIdx.x * 256 + threadIdx.x;
  if (idx >= NV * COUT) return;
  const int i = idx / COUT, c = idx % COUT;
  float v = 0.f;
  if (i < *nactp) {
    const float y = fmaf(x[idx], scale[c], shift[c]);
    v = (y > 0.f) ? y : 0.f;   // also canonicalizes -0 -> +0
  }
  x[idx] = v;
}

// ---------------- pooling ----------------
__global__ __launch_bounds__(256) void k_poolkey(const int* __restrict__ c,
    long long* __restrict__ pk, const int* __restrict__ nactp,
    int sd, int sh, int sw, int oD, int oH, int oW)
{
  const int i = blockIdx.x * 256 + threadIdx.x;
  if (i >= NV) return;
  if (i < *nactp) {
    const int b = c[i*4+0];
    const int d = c[i*4+1] / sd, h = c[i*4+2] / sh, w = c[i*4+3] / sw;
    pk[i] = (((long long)b*oD + d)*oH + h)*(long long)oW + w;
  } else pk[i] = BIGK;
}

__global__ __launch_bounds__(1024) void k_sortcompact(const long long* __restrict__ pk,
    int* __restrict__ cNew, int* __restrict__ map, int* __restrict__ nactOut,
    int D, int H, int Wd)
{
  __shared__ long long sk[NV];
  __shared__ int si[NV];
  __shared__ int sc[NV];
  __shared__ int s2[NV];
  const int tid = threadIdx.x;
  for (int e = 0; e < 2; ++e) { const int t = tid + e*1024; sk[t] = pk[t]; si[t] = t; }
  __syncthreads();
  for (int k = 2; k <= NV; k <<= 1)
    for (int j = k >> 1; j > 0; j >>= 1) {
      for (int e = 0; e < 2; ++e) {
        const int i = tid + e*1024;
        const int ixj = i ^ j;
        if (ixj > i) {
          const bool up = ((i & k) == 0);
          const long long a = sk[i], bb = sk[ixj];
          const bool sw = up ? (a > bb) : (a < bb);
          if (sw) { sk[i] = bb; sk[ixj] = a; const int t2 = si[i]; si[i] = si[ixj]; si[ixj] = t2; }
        }
      }
      __syncthreads();
    }
  for (int e = 0; e < 2; ++e) {
    const int t = tid + e*1024;
    sc[t] = (sk[t] != BIGK && (t == 0 || sk[t] != sk[t-1])) ? 1 : 0;
  }
  __syncthreads();
  for (int d2 = 1; d2 < NV; d2 <<= 1) {
    for (int e = 0; e < 2; ++e) { const int t = tid + e*1024; s2[t] = sc[t] + ((t >= d2) ? sc[t - d2] : 0); }
    __syncthreads();
    for (int e = 0; e < 2; ++e) { const int t = tid + e*1024; sc[t] = s2[t]; }
    __syncthreads();
  }
  for (int e = 0; e < 2; ++e) {
    const int t = tid + e*1024;
    const long long key = sk[t];
    if (key != BIGK) {
      const int g = sc[t] - 1;
      map[si[t]] = g;
      if (t == 0 || sk[t-1] != key) {
        const int w = (int)(key % Wd);
        long long r = key / Wd;
        const int h = (int)(r % H); r /= H;
        const int d = (int)(r % D);
        const int b = (int)(r / D);
        cNew[g*4+0] = b; cNew[g*4+1] = d; cNew[g*4+2] = h; cNew[g*4+3] = w;
      }
    }
  }
  if (tid == 0) *nactOut = sc[NV-1];
}

__global__ __launch_bounds__(256) void k_zero(float* __restrict__ x, int n) {
  const int idx = blockIdx.x * 256 + threadIdx.x;
  if (idx < n) x[idx] = 0.f;
}

template<int C>
__global__ __launch_bounds__(256) void k_pscatter(const float* __restrict__ src,
    float* __restrict__ dst, const int* __restrict__ map, const int* __restrict__ nactp)
{
  const int idx = blockIdx.x * 256 + threadIdx.x;
  const int i = idx / C;
  if (i >= *nactp) return;
  atomicMax((unsigned*)&dst[map[i] * C + (idx % C)], __float_as_uint(src[idx]));
}

// ---------------- final dense scatter ----------------
__global__ __launch_bounds__(256) void k_out(const float* __restrict__ f,
    const int* __restrict__ c, float* __restrict__ out, const int* __restrict__ nactp)
{
  const int idx = blockIdx.x * 256 + threadIdx.x;
  const int i = idx >> 9, ch = idx & 511;
  if (i >= *nactp) return;
  const int b = c[i*4+0], d = c[i*4+1], h = c[i*4+2], w = c[i*4+3];
  out[ (((b*512 + ch)*2 + d)*111 + h)*98 + w ] = f[idx];
}

// ---------------- host orchestration ----------------
template<int K, int CIN, int C>
static void run_stage(hipStream_t stream, int s,
    const float* Wa, const float* Ga, const float* Ba,
    const float* Wb, const float* Gb, const float* Bb,
    float* fX, float* fY, int* cX, int* cY,
    int D, int H, int W, int pd, int ph, int pw, int oD, int oH, int oW,
    long long* hk, int* hv, long long* pkey, int* pslot, int* cnt, int* map,
    int* nact, float* scale, float* shift,
    int* ocnt, int* obase, int* olist, float* P)
{
  constexpr int K3 = K*K*K;
  constexpr int CTR = K3/2;
  constexpr int NCH  = (C + 255) / 256;
  constexpr int KS1  = (CIN + 63) / 64;
  constexpr int KS2  = (C + 63) / 64;
  const int* na = nact + s;
  k_hclear<<<HSIZE/256, 256, 0, stream>>>(hk, ocnt);
  k_hinsert<<<NV/256, 256, 0, stream>>>(cX, hk, hv, na, D, H, W);
  k_hits<K><<<NV/4, 256, 0, stream>>>(cX, hk, hv, na, pslot, cnt, ocnt, olist, D, H, W);
  k_oscan<<<1, 512, 0, stream>>>(ocnt, obase);

  k_gemm<CIN, C><<<NV/8, 256, 0, stream>>>(fX, Wa + (size_t)CTR*CIN*C, fY, na);
  k_pgemm<CIN, C><<<K3*NCH*KS1, 256, 0, stream>>>(fX, Wa, P, ocnt, obase, olist);
  k_psum<C, KS1><<<NV*C/256, 256, 0, stream>>>(fY, P, pslot, obase, cnt, na);
  k_bnstats<C><<<C, 256, 0, stream>>>(fY, Ga, Ba, scale, shift, na);
  k_bnrelu<C><<<NV*C/256, 256, 0, stream>>>(fY, scale, shift, na);

  k_gemm<C, C><<<NV/8, 256, 0, stream>>>(fY, Wb + (size_t)CTR*C*C, fX, na);
  k_pgemm<C, C><<<K3*NCH*KS2, 256, 0, stream>>>(fY, Wb, P, ocnt, obase, olist);
  k_psum<C, KS2><<<NV*C/256, 256, 0, stream>>>(fX, P, pslot, obase, cnt, na);
  k_bnstats<C><<<C, 256, 0, stream>>>(fX, Gb, Bb, scale, shift, na);
  k_bnrelu<C><<<NV*C/256, 256, 0, stream>>>(fX, scale, shift, na);

  k_poolkey<<<NV/256, 256, 0, stream>>>(cX, pkey, na, pd, ph, pw, oD, oH, oW);
  k_sortcompact<<<1, 1024, 0, stream>>>(pkey, cY, map, nact + s + 1, oD, oH, oW);
  k_zero<<<NV*C/256, 256, 0, stream>>>(fY, NV*C);
  k_pscatter<C><<<NV*C/256, 256, 0, stream>>>(fX, fY, map, na);
}

extern "C" void kernel_launch(void* const* d_in, const int* in_sizes, int n_in,
                              void* d_out, int out_size, void* d_ws, size_t ws_size,
                              hipStream_t stream)
{
  const float* vf    = (const float*)d_in[0];
  const int*   coors = (const int*)d_in[1];
  const float *Wl[10], *Gl[10], *Bl[10];
  for (int i = 0; i < 10; ++i) {
    Wl[i] = (const float*)d_in[3 + 3*i];
    Gl[i] = (const float*)d_in[4 + 3*i];
    Bl[i] = (const float*)d_in[5 + 3*i];
  }

  char* p = (char*)d_ws;
  auto alloc = [&](size_t bytes) { char* q = p; p += (bytes + 255) & ~(size_t)255; return q; };
  float*     fB    = (float*)    alloc((size_t)NV*512*4);
  long long* hk    = (long long*)alloc((size_t)HSIZE*8);
  long long* pkey  = (long long*)alloc((size_t)NV*8);
  int*       hv    = (int*)      alloc((size_t)HSIZE*4);
  int*       cA    = (int*)      alloc((size_t)NV*4*4);
  int*       cB    = (int*)      alloc((size_t)NV*4*4);
  int*       pslot = (int*)      alloc((size_t)NV*MAXE*4);
  int*       cnt   = (int*)      alloc((size_t)NV*4);
  int*       map   = (int*)      alloc((size_t)NV*4);
  int*       nact  = (int*)      alloc(8*4);
  float*     scale = (float*)    alloc(512*4);
  float*     shift = (float*)    alloc(512*4);
  int*       ocnt  = (int*)      alloc((size_t)K3MAX*4);
  int*       obase = (int*)      alloc((size_t)K3MAX*4);

  // scratch aliased into d_out (89 MB); all dead before the final memset
  float* fA    = (float*)d_out;                                   // 4 MB
  float* P     = (float*)((char*)d_out + (size_t)8*1024*1024);    // worst ~32 MB
  int*   olist = (int*)  ((char*)d_out + (size_t)48*1024*1024);   // 343*256*4 = 351 KB

  k_init<<<NV/256, 256, 0, stream>>>(vf, coors, cA, fA, nact);

  run_stage<7, 1, 64>  (stream, 0, Wl[0],Gl[0],Bl[0], Wl[1],Gl[1],Bl[1],
    fA, fB, cA, cB, 216, 7992, 7056, 3, 3, 3, 72, 2664, 2352,
    hk, hv, pkey, pslot, cnt, map, nact, scale, shift, ocnt, obase, olist, P);
  run_stage<7, 64, 128>(stream, 1, Wl[2],Gl[2],Bl[2], Wl[3],Gl[3],Bl[3],
    fB, fA, cB, cA, 72, 2664, 2352, 3, 3, 3, 24, 888, 784,
    hk, hv, pkey, pslot, cnt, map, nact, scale, shift, ocnt, obase, olist, P);
  run_stage<5, 128, 256>(stream, 2, Wl[4],Gl[4],Bl[4], Wl[5],Gl[5],Bl[5],
    fA, fB, cA, cB, 24, 888, 784, 3, 2, 2, 8, 444, 392,
    hk, hv, pkey, pslot, cnt, map, nact, scale, shift, ocnt, obase, olist, P);
  run_stage<3, 256, 384>(stream, 3, Wl[6],Gl[6],Bl[6], Wl[7],Gl[7],Bl[7],
    fB, fA, cB, cA, 8, 444, 392, 2, 2, 2, 4, 222, 196,
    hk, hv, pkey, pslot, cnt, map, nact, scale, shift, ocnt, obase, olist, P);
  run_stage<3, 384, 512>(stream, 4, Wl[8],Gl[8],Bl[8], Wl[9],Gl[9],Bl[9],
    fA, fB, cA, cB, 4, 222, 196, 2, 2, 2, 2, 111, 98,
    hk, hv, pkey, pslot, cnt, map, nact, scale, shift, ocnt, obase, olist, P);

  hipMemsetAsync(d_out, 0, (size_t)out_size * sizeof(float), stream);
  k_out<<<NV*512/256, 256, 0, stream>>>(fB, cB, (float*)d_out, nact + 5);
}

// Round 4
// 945.468 us; speedup vs baseline: 2.9319x; 1.0527x over previous
//
#include <hip/hip_runtime.h>
#include <climits>
#include <cstdint>

#define NV    2048
#define MAXE  344
#define HSIZE 8192
#define HMASK 8191
#define BIGK  LLONG_MAX
#define K3MAX 343
#define MAXP  256

__device__ __forceinline__ unsigned hashk(long long k) {
  unsigned long long x = (unsigned long long)k * 0x9E3779B97F4A7C15ull;
  return (unsigned)(x >> 51) & HMASK;
}

// ---------------- init ----------------
__global__ __launch_bounds__(256) void k_init(const float* __restrict__ vf,
    const int* __restrict__ coors, int* __restrict__ cA, float* __restrict__ fA,
    int* __restrict__ nact)
{
  int i = blockIdx.x * 256 + threadIdx.x;
  if (i == 0) nact[0] = NV;
  if (i >= NV) return;
  cA[i*4+0] = coors[i*4+0];
  cA[i*4+1] = coors[i*4+1];
  cA[i*4+2] = coors[i*4+2];
  cA[i*4+3] = coors[i*4+3];
  fA[i] = vf[i];
}

// ---------------- hash ----------------
__global__ __launch_bounds__(256) void k_hclear(long long* __restrict__ hk,
    int* __restrict__ ocnt)
{
  int i = blockIdx.x * 256 + threadIdx.x;
  if (i < HSIZE) hk[i] = -1LL;
  if (i < K3MAX) ocnt[i] = 0;
}

__global__ __launch_bounds__(256) void k_hinsert(const int* __restrict__ c,
    long long* __restrict__ hk, int* __restrict__ hv, const int* __restrict__ nactp,
    int D, int H, int Wd)
{
  int i = blockIdx.x * 256 + threadIdx.x;
  if (i >= NV || i >= *nactp) return;
  long long key = (((long long)c[i*4+0]*D + c[i*4+1])*H + c[i*4+2])*(long long)Wd + c[i*4+3];
  unsigned h = hashk(key);
  while (true) {
    unsigned long long old = atomicCAS((unsigned long long*)&hk[h], ~0ull, (unsigned long long)key);
    if (old == ~0ull) { hv[h] = i; break; }
    h = (h + 1) & HMASK;
  }
}

// ---------------- neighbor hit lists (one wave per site), grouped by offset ----------------
template<int K>
__global__ __launch_bounds__(256) void k_hits(const int* __restrict__ c,
    const long long* __restrict__ hk, const int* __restrict__ hv,
    const int* __restrict__ nactp, int* __restrict__ pslot, int* __restrict__ cnt,
    int* __restrict__ ocnt, int* __restrict__ olist,
    int D, int H, int Wd)
{
  constexpr int K3 = K*K*K, R = K/2, CTR = K3/2;
  const int site = blockIdx.x * 4 + (threadIdx.x >> 6);
  const int lane = threadIdx.x & 63;
  const int nact = *nactp;
  if (site >= NV) return;
  if (site >= nact) { if (lane == 0) cnt[site] = 0; return; }
  const int b = c[site*4+0], d = c[site*4+1], hc = c[site*4+2], w = c[site*4+3];
  int base = 0;
  for (int o0 = 0; o0 < K3; o0 += 64) {
    const int o = o0 + lane;
    int j = -1;
    if (o < K3 && o != CTR) {
      const int dz = o/(K*K) - R, dy = (o/K)%K - R, dx = o%K - R;
      const int nd = d+dz, nh = hc+dy, nw = w+dx;
      if (nd >= 0 && nd < D && nh >= 0 && nh < H && nw >= 0 && nw < Wd) {
        const long long key = (((long long)b*D + nd)*H + nh)*(long long)Wd + nw;
        unsigned hs = hashk(key);
        while (true) {
          const long long kk = hk[hs];
          if (kk == -1LL) break;
          if (kk == key) { j = hv[hs]; break; }
          hs = (hs + 1) & HMASK;
        }
      }
    }
    const unsigned long long m = __ballot(j >= 0);
    if (j >= 0) {
      const int pos = __popcll(m & ((1ull << lane) - 1ull));
      const int p = atomicAdd(&ocnt[o], 1);
      int tag = -1;
      if (p < MAXP) { olist[o * MAXP + p] = (site << 12) | j; tag = (o << 8) | p; }
      pslot[site * MAXE + base + pos] = tag;
    }
    base += __popcll(m);
  }
  if (lane == 0) cnt[site] = base;
}

// ---------------- exclusive scan of per-offset hit counts -> compact slot bases ----------------
__global__ __launch_bounds__(512) void k_oscan(const int* __restrict__ ocnt,
    int* __restrict__ obase)
{
  __shared__ int s[512];
  const int t = threadIdx.x;
  const int v = (t < K3MAX) ? min(ocnt[t], MAXP) : 0;
  s[t] = v;
  __syncthreads();
  for (int d = 1; d < 512; d <<= 1) {
    const int x = (t >= d) ? s[t - d] : 0;
    __syncthreads();
    s[t] += x;
    __syncthreads();
  }
  if (t < K3MAX) obase[t] = s[t] - v;
}

// ---------------- dense center GEMM: out = f @ Wc ----------------
template<int CIN, int COUT>
__global__ __launch_bounds__(256) void k_gemm(const float* __restrict__ f,
    const float* __restrict__ Wc, float* __restrict__ out, const int* __restrict__ nactp)
{
  constexpr int TM  = 8;
  constexpr int CPT = (COUT + 255) / 256;
  constexpr int RG  = (COUT < 256) ? (256 / COUT) : 1;
  constexpr int RPT = TM / RG;
  __shared__ float as[TM * CIN];
  const int tid  = threadIdx.x;
  const int row0 = blockIdx.x * TM;
  const int nact = *nactp;
  const int cbase = (RG > 1) ? (tid % COUT) : tid;
  const int rbase = (RG > 1) ? (tid / COUT) * RPT : 0;
  if (row0 >= nact) {
    #pragma unroll
    for (int i = 0; i < RPT; ++i)
      #pragma unroll
      for (int j = 0; j < CPT; ++j) {
        int cc = cbase + j * 256;
        if (cc < COUT) out[(row0 + rbase + i) * COUT + cc] = 0.f;
      }
    return;
  }
  for (int idx = tid; idx < TM * CIN; idx += 256)
    as[idx] = f[row0 * CIN + idx];
  __syncthreads();
  float acc[RPT][CPT];
  #pragma unroll
  for (int i = 0; i < RPT; ++i)
    #pragma unroll
    for (int j = 0; j < CPT; ++j) acc[i][j] = 0.f;
  #pragma unroll 4
  for (int k = 0; k < CIN; ++k) {
    float wv[CPT];
    #pragma unroll
    for (int j = 0; j < CPT; ++j) {
      int cc = cbase + j * 256;
      wv[j] = (cc < COUT) ? Wc[k * COUT + cc] : 0.f;
    }
    #pragma unroll
    for (int i = 0; i < RPT; ++i) {
      const float av = as[(rbase + i) * CIN + k];
      #pragma unroll
      for (int j = 0; j < CPT; ++j) acc[i][j] += av * wv[j];
    }
  }
  #pragma unroll
  for (int i = 0; i < RPT; ++i)
    #pragma unroll
    for (int j = 0; j < CPT; ++j) {
      int cc = cbase + j * 256;
      if (cc < COUT) out[(row0 + rbase + i) * COUT + cc] = acc[i][j];
    }
}

// ---------------- phase 1: per-(offset, k-slice) partial GEMM, float4 W stream ----------------
// P[(slot*KS_TOT + ks)*COUT + c..c+3] = sum_{k in slice ks} f[j][k] * W[o][k][c..c+3]
template<int CIN, int COUT>
__global__ __launch_bounds__(256) void k_pgemm(const float* __restrict__ f,
    const float* __restrict__ Wall, float* __restrict__ P,
    const int* __restrict__ ocnt, const int* __restrict__ obase,
    const int* __restrict__ olist)
{
  constexpr int KSUB = 32;
  constexpr int CPW  = COUT / 4;                       // threads per k-slice
  constexpr int NKQ  = (256 / CPW) < 1 ? 1 : (256 / CPW);
  constexpr int KS_TOT = (CIN + KSUB - 1) / KSUB;
  constexpr int NKB  = (KS_TOT + NKQ - 1) / NKQ;       // grid k-blocks
  constexpr int KLEN = (CIN >= KSUB) ? KSUB : CIN;     // CIN%32==0 for CIN>1
  constexpr int KBLK = (NKQ*KSUB < CIN) ? NKQ*KSUB : CIN;
  constexpr int HB   = 8;
  constexpr int SLOTCAP = (40*1024*1024) / (KS_TOT*COUT*4);

  const int o  = blockIdx.x / NKB;
  const int kb = blockIdx.x - o*NKB;
  int m = ocnt[o];
  if (m == 0) return;
  if (m > MAXP) m = MAXP;
  const int sbase = obase[o];
  const int tid = threadIdx.x;
  const int kq  = tid / CPW;
  const int cq  = tid - kq*CPW;
  const int ks  = kb*NKQ + kq;
  const bool act = (kq < NKQ) && (ks < KS_TOT);
  const int kbase = kb * (NKQ*KSUB);
  const int k0 = ks * KSUB;
  const int c  = cq * 4;
  const int kblk_eff = (CIN - kbase < KBLK) ? (CIN - kbase) : KBLK;
  __shared__ float fs[HB][KBLK];
  const float* __restrict__ Wo = Wall + (size_t)o * (CIN*COUT);

  for (int p0 = 0; p0 < m; p0 += HB) {
    const int hb = min(HB, m - p0);
    __syncthreads();
    for (int idx = tid; idx < hb*kblk_eff; idx += 256) {
      const int h = idx / kblk_eff, k = idx - h*kblk_eff;
      const int j = olist[o*MAXP + p0 + h] & 0xFFF;
      fs[h][k] = f[j*CIN + kbase + k];
    }
    __syncthreads();
    if (act) {
      float4 acc[HB];
      #pragma unroll
      for (int h = 0; h < HB; ++h) { acc[h].x=0.f; acc[h].y=0.f; acc[h].z=0.f; acc[h].w=0.f; }
      #pragma unroll
      for (int k = 0; k < KLEN; ++k) {
        const float4 wv = *(const float4*)&Wo[(size_t)(k0+k)*COUT + c];
        const int lk = kq*KSUB + k;
        #pragma unroll
        for (int h = 0; h < HB; ++h) {
          const float fv = fs[h][lk];
          acc[h].x = fmaf(fv, wv.x, acc[h].x);
          acc[h].y = fmaf(fv, wv.y, acc[h].y);
          acc[h].z = fmaf(fv, wv.z, acc[h].z);
          acc[h].w = fmaf(fv, wv.w, acc[h].w);
        }
      }
      for (int h = 0; h < hb; ++h) {
        const int slot = sbase + p0 + h;
        if (slot < SLOTCAP)
          *(float4*)&P[((size_t)slot*KS_TOT + ks)*COUT + c] = acc[h];
      }
    }
  }
}

// ---------------- phase 2: per-site deterministic sum of partials ----------------
template<int COUT, int KS>
__global__ __launch_bounds__(256) void k_psum(float* __restrict__ out,
    const float* __restrict__ P, const int* __restrict__ pslot,
    const int* __restrict__ obase, const int* __restrict__ cnt,
    const int* __restrict__ nactp)
{
  constexpr int SLOTCAP = (40*1024*1024) / (KS*COUT*4);
  const int idx = blockIdx.x * 256 + threadIdx.x;
  const int i = idx / COUT;
  if (i >= *nactp) return;
  const int n = cnt[i];
  if (n == 0) return;
  const int cc = idx - i * COUT;
  float acc = 0.f;
  for (int h = 0; h < n; ++h) {
    const int e = pslot[i * MAXE + h];
    if (e < 0) continue;
    const int slot = obase[e >> 8] + (e & 0xFF);
    if (slot >= SLOTCAP) continue;
    #pragma unroll
    for (int ks = 0; ks < KS; ++ks)
      acc += P[((size_t)slot * KS + ks) * COUT + cc];
  }
  out[idx] += acc;
}

// ---------------- BN stats -> scale/shift ----------------
template<int COUT>
__global__ __launch_bounds__(256) void k_bnstats(const float* __restrict__ x,
    const float* __restrict__ g, const float* __restrict__ b,
    float* __restrict__ scale, float* __restrict__ shift, const int* __restrict__ nactp)
{
  const int c = blockIdx.x;
  const int tid = threadIdx.x;
  double s1 = 0.0, s2 = 0.0;
  for (int r = tid; r < NV; r += 256) {
    const double v = (double)x[r * COUT + c];
    s1 += v; s2 += v * v;
  }
  __shared__ double r1[256], r2[256];
  r1[tid] = s1; r2[tid] = s2;
  __syncthreads();
  for (int off = 128; off > 0; off >>= 1) {
    if (tid < off) { r1[tid] += r1[tid + off]; r2[tid] += r2[tid + off]; }
    __syncthreads();
  }
  if (tid == 0) {
    const double n = (double)(*nactp);
    const double mu = r1[0] / n;
    double var = r2[0] / n - mu * mu;
    if (var < 0.0) var = 0.0;
    const double sc = (double)g[c] / sqrt(var + 1e-4);
    scale[c] = (float)sc;
    shift[c] = (float)((double)b[c] - mu * sc);
  }
}

// ---------------- BN apply + ReLU (in place) ----------------
template<int COUT>
__global__ __launch_bounds__(256) void k_bnrelu(float* __restrict__ x,
    const float* __restrict__ scale, const float* __restrict__ shift,
    const int* __restrict__ nactp)
{
  const int idx = blockIdx.x * 256 + threadIdx.x;
  if (idx >= NV * COUT) return;
  const int i = idx / COUT, c = idx % COUT;
  float v = 0.f;
  if (i < *nactp) {
    const float y = fmaf(x[idx], scale[c], shift[c]);
    v = (y > 0.f) ? y : 0.f;   // also canonicalizes -0 -> +0
  }
  x[idx] = v;
}

// ---------------- pooling ----------------
__global__ __launch_bounds__(256) void k_poolkey(const int* __restrict__ c,
    long long* __restrict__ pk, const int* __restrict__ nactp,
    int sd, int sh, int sw, int oD, int oH, int oW)
{
  const int i = blockIdx.x * 256 + threadIdx.x;
  if (i >= NV) return;
  if (i < *nactp) {
    const int b = c[i*4+0];
    const int d = c[i*4+1] / sd, h = c[i*4+2] / sh, w = c[i*4+3] / sw;
    pk[i] = (((long long)b*oD + d)*oH + h)*(long long)oW + w;
  } else pk[i] = BIGK;
}

__global__ __launch_bounds__(1024) void k_sortcompact(const long long* __restrict__ pk,
    int* __restrict__ cNew, int* __restrict__ map, int* __restrict__ nactOut,
    int D, int H, int Wd)
{
  __shared__ long long sk[NV];
  __shared__ int si[NV];
  __shared__ int sc[NV];
  __shared__ int s2[NV];
  const int tid = threadIdx.x;
  for (int e = 0; e < 2; ++e) { const int t = tid + e*1024; sk[t] = pk[t]; si[t] = t; }
  __syncthreads();
  for (int k = 2; k <= NV; k <<= 1)
    for (int j = k >> 1; j > 0; j >>= 1) {
      for (int e = 0; e < 2; ++e) {
        const int i = tid + e*1024;
        const int ixj = i ^ j;
        if (ixj > i) {
          const bool up = ((i & k) == 0);
          const long long a = sk[i], bb = sk[ixj];
          const bool sw = up ? (a > bb) : (a < bb);
          if (sw) { sk[i] = bb; sk[ixj] = a; const int t2 = si[i]; si[i] = si[ixj]; si[ixj] = t2; }
        }
      }
      __syncthreads();
    }
  for (int e = 0; e < 2; ++e) {
    const int t = tid + e*1024;
    sc[t] = (sk[t] != BIGK && (t == 0 || sk[t] != sk[t-1])) ? 1 : 0;
  }
  __syncthreads();
  for (int d2 = 1; d2 < NV; d2 <<= 1) {
    for (int e = 0; e < 2; ++e) { const int t = tid + e*1024; s2[t] = sc[t] + ((t >= d2) ? sc[t - d2] : 0); }
    __syncthreads();
    for (int e = 0; e < 2; ++e) { const int t = tid + e*1024; sc[t] = s2[t]; }
    __syncthreads();
  }
  for (int e = 0; e < 2; ++e) {
    const int t = tid + e*1024;
    const long long key = sk[t];
    if (key != BIGK) {
      const int g = sc[t] - 1;
      map[si[t]] = g;
      if (t == 0 || sk[t-1] != key) {
        const int w = (int)(key % Wd);
        long long r = key / Wd;
        const int h = (int)(r % H); r /= H;
        const int d = (int)(r % D);
        const int b = (int)(r / D);
        cNew[g*4+0] = b; cNew[g*4+1] = d; cNew[g*4+2] = h; cNew[g*4+3] = w;
      }
    }
  }
  if (tid == 0) *nactOut = sc[NV-1];
}

__global__ __launch_bounds__(256) void k_zero(float* __restrict__ x, int n) {
  const int idx = blockIdx.x * 256 + threadIdx.x;
  if (idx < n) x[idx] = 0.f;
}

template<int C>
__global__ __launch_bounds__(256) void k_pscatter(const float* __restrict__ src,
    float* __restrict__ dst, const int* __restrict__ map, const int* __restrict__ nactp)
{
  const int idx = blockIdx.x * 256 + threadIdx.x;
  const int i = idx / C;
  if (i >= *nactp) return;
  atomicMax((unsigned*)&dst[map[i] * C + (idx % C)], __float_as_uint(src[idx]));
}

// ---------------- final dense scatter ----------------
__global__ __launch_bounds__(256) void k_out(const float* __restrict__ f,
    const int* __restrict__ c, float* __restrict__ out, const int* __restrict__ nactp)
{
  const int idx = blockIdx.x * 256 + threadIdx.x;
  const int i = idx >> 9, ch = idx & 511;
  if (i >= *nactp) return;
  const int b = c[i*4+0], d = c[i*4+1], h = c[i*4+2], w = c[i*4+3];
  out[ (((b*512 + ch)*2 + d)*111 + h)*98 + w ] = f[idx];
}

// ---------------- host orchestration ----------------
template<int K, int CIN, int C>
static void run_stage(hipStream_t stream, int s,
    const float* Wa, const float* Ga, const float* Ba,
    const float* Wb, const float* Gb, const float* Bb,
    float* fX, float* fY, int* cX, int* cY,
    int D, int H, int W, int pd, int ph, int pw, int oD, int oH, int oW,
    long long* hk, int* hv, long long* pkey, int* pslot, int* cnt, int* map,
    int* nact, float* scale, float* shift,
    int* ocnt, int* obase, int* olist, float* P)
{
  constexpr int K3 = K*K*K;
  constexpr int CTR = K3/2;
  constexpr int CPW = C / 4;
  constexpr int NKQ = (256 / CPW) < 1 ? 1 : (256 / CPW);
  constexpr int KS1 = (CIN + 31) / 32;
  constexpr int KS2 = (C + 31) / 32;
  constexpr int NKB1 = (KS1 + NKQ - 1) / NKQ;
  constexpr int NKB2 = (KS2 + NKQ - 1) / NKQ;
  const int* na = nact + s;
  k_hclear<<<HSIZE/256, 256, 0, stream>>>(hk, ocnt);
  k_hinsert<<<NV/256, 256, 0, stream>>>(cX, hk, hv, na, D, H, W);
  k_hits<K><<<NV/4, 256, 0, stream>>>(cX, hk, hv, na, pslot, cnt, ocnt, olist, D, H, W);
  k_oscan<<<1, 512, 0, stream>>>(ocnt, obase);

  k_gemm<CIN, C><<<NV/8, 256, 0, stream>>>(fX, Wa + (size_t)CTR*CIN*C, fY, na);
  k_pgemm<CIN, C><<<K3*NKB1, 256, 0, stream>>>(fX, Wa, P, ocnt, obase, olist);
  k_psum<C, KS1><<<NV*C/256, 256, 0, stream>>>(fY, P, pslot, obase, cnt, na);
  k_bnstats<C><<<C, 256, 0, stream>>>(fY, Ga, Ba, scale, shift, na);
  k_bnrelu<C><<<NV*C/256, 256, 0, stream>>>(fY, scale, shift, na);

  k_gemm<C, C><<<NV/8, 256, 0, stream>>>(fY, Wb + (size_t)CTR*C*C, fX, na);
  k_pgemm<C, C><<<K3*NKB2, 256, 0, stream>>>(fY, Wb, P, ocnt, obase, olist);
  k_psum<C, KS2><<<NV*C/256, 256, 0, stream>>>(fX, P, pslot, obase, cnt, na);
  k_bnstats<C><<<C, 256, 0, stream>>>(fX, Gb, Bb, scale, shift, na);
  k_bnrelu<C><<<NV*C/256, 256, 0, stream>>>(fX, scale, shift, na);

  k_poolkey<<<NV/256, 256, 0, stream>>>(cX, pkey, na, pd, ph, pw, oD, oH, oW);
  k_sortcompact<<<1, 1024, 0, stream>>>(pkey, cY, map, nact + s + 1, oD, oH, oW);
  k_zero<<<NV*C/256, 256, 0, stream>>>(fY, NV*C);
  k_pscatter<C><<<NV*C/256, 256, 0, stream>>>(fX, fY, map, na);
}

extern "C" void kernel_launch(void* const* d_in, const int* in_sizes, int n_in,
                              void* d_out, int out_size, void* d_ws, size_t ws_size,
                              hipStream_t stream)
{
  const float* vf    = (const float*)d_in[0];
  const int*   coors = (const int*)d_in[1];
  const float *Wl[10], *Gl[10], *Bl[10];
  for (int i = 0; i < 10; ++i) {
    Wl[i] = (const float*)d_in[3 + 3*i];
    Gl[i] = (const float*)d_in[4 + 3*i];
    Bl[i] = (const float*)d_in[5 + 3*i];
  }

  char* p = (char*)d_ws;
  auto alloc = [&](size_t bytes) { char* q = p; p += (bytes + 255) & ~(size_t)255; return q; };
  float*     fB    = (float*)    alloc((size_t)NV*512*4);
  long long* hk    = (long long*)alloc((size_t)HSIZE*8);
  long long* pkey  = (long long*)alloc((size_t)NV*8);
  int*       hv    = (int*)      alloc((size_t)HSIZE*4);
  int*       cA    = (int*)      alloc((size_t)NV*4*4);
  int*       cB    = (int*)      alloc((size_t)NV*4*4);
  int*       pslot = (int*)      alloc((size_t)NV*MAXE*4);
  int*       cnt   = (int*)      alloc((size_t)NV*4);
  int*       map   = (int*)      alloc((size_t)NV*4);
  int*       nact  = (int*)      alloc(8*4);
  float*     scale = (float*)    alloc(512*4);
  float*     shift = (float*)    alloc(512*4);
  int*       ocnt  = (int*)      alloc((size_t)K3MAX*4);
  int*       obase = (int*)      alloc((size_t)K3MAX*4);

  // scratch aliased into d_out (89 MB); all dead before the final memset
  float* fA    = (float*)d_out;                                   // 4 MB
  float* P     = (float*)((char*)d_out + (size_t)8*1024*1024);    // 40 MB budget (SLOTCAP-guarded)
  int*   olist = (int*)  ((char*)d_out + (size_t)48*1024*1024);   // 343*256*4 = 351 KB

  k_init<<<NV/256, 256, 0, stream>>>(vf, coors, cA, fA, nact);

  run_stage<7, 1, 64>  (stream, 0, Wl[0],Gl[0],Bl[0], Wl[1],Gl[1],Bl[1],
    fA, fB, cA, cB, 216, 7992, 7056, 3, 3, 3, 72, 2664, 2352,
    hk, hv, pkey, pslot, cnt, map, nact, scale, shift, ocnt, obase, olist, P);
  run_stage<7, 64, 128>(stream, 1, Wl[2],Gl[2],Bl[2], Wl[3],Gl[3],Bl[3],
    fB, fA, cB, cA, 72, 2664, 2352, 3, 3, 3, 24, 888, 784,
    hk, hv, pkey, pslot, cnt, map, nact, scale, shift, ocnt, obase, olist, P);
  run_stage<5, 128, 256>(stream, 2, Wl[4],Gl[4],Bl[4], Wl[5],Gl[5],Bl[5],
    fA, fB, cA, cB, 24, 888, 784, 3, 2, 2, 8, 444, 392,
    hk, hv, pkey, pslot, cnt, map, nact, scale, shift, ocnt, obase, olist, P);
  run_stage<3, 256, 384>(stream, 3, Wl[6],Gl[6],Bl[6], Wl[7],Gl[7],Bl[7],
    fB, fA, cB, cA, 8, 444, 392, 2, 2, 2, 4, 222, 196,
    hk, hv, pkey, pslot, cnt, map, nact, scale, shift, ocnt, obase, olist, P);
  run_stage<3, 384, 512>(stream, 4, Wl[8],Gl[8],Bl[8], Wl[9],Gl[9],Bl[9],
    fA, fB, cA, cB, 4, 222, 196, 2, 2, 2, 2, 111, 98,
    hk, hv, pkey, pslot, cnt, map, nact, scale, shift, ocnt, obase, olist, P);

  hipMemsetAsync(d_out, 0, (size_t)out_size * sizeof(float), stream);
  k_out<<<NV*512/256, 256, 0, stream>>>(fB, cB, (float*)d_out, nact + 5);
}

// Round 5
// 855.420 us; speedup vs baseline: 3.2406x; 1.1053x over previous
//
#include <hip/hip_runtime.h>
#include <climits>
#include <cstdint>

#define NV    2048
#define MAXE  344
#define HSIZE 8192
#define HMASK 8191
#define BIGK  LLONG_MAX
#define K3MAX 343
#define MAXP  256

__device__ __forceinline__ unsigned hashk(long long k) {
  unsigned long long x = (unsigned long long)k * 0x9E3779B97F4A7C15ull;
  return (unsigned)(x >> 51) & HMASK;
}

// ---------------- init ----------------
__global__ __launch_bounds__(256) void k_init(const float* __restrict__ vf,
    const int* __restrict__ coors, int* __restrict__ cA, float* __restrict__ fA,
    int* __restrict__ nact)
{
  int i = blockIdx.x * 256 + threadIdx.x;
  if (i == 0) nact[0] = NV;
  if (i >= NV) return;
  cA[i*4+0] = coors[i*4+0];
  cA[i*4+1] = coors[i*4+1];
  cA[i*4+2] = coors[i*4+2];
  cA[i*4+3] = coors[i*4+3];
  fA[i] = vf[i];
}

// ---------------- hash ----------------
__global__ __launch_bounds__(256) void k_hclear(long long* __restrict__ hk,
    int* __restrict__ ocnt)
{
  int i = blockIdx.x * 256 + threadIdx.x;
  if (i < HSIZE) hk[i] = -1LL;
  if (i < K3MAX) ocnt[i] = 0;
}

__global__ __launch_bounds__(256) void k_hinsert(const int* __restrict__ c,
    long long* __restrict__ hk, int* __restrict__ hv, const int* __restrict__ nactp,
    int D, int H, int Wd)
{
  int i = blockIdx.x * 256 + threadIdx.x;
  if (i >= NV || i >= *nactp) return;
  long long key = (((long long)c[i*4+0]*D + c[i*4+1])*H + c[i*4+2])*(long long)Wd + c[i*4+3];
  unsigned h = hashk(key);
  while (true) {
    unsigned long long old = atomicCAS((unsigned long long*)&hk[h], ~0ull, (unsigned long long)key);
    if (old == ~0ull) { hv[h] = i; break; }
    h = (h + 1) & HMASK;
  }
}

// ---------------- neighbor hit lists (one wave per site), grouped by offset ----------------
template<int K>
__global__ __launch_bounds__(256) void k_hits(const int* __restrict__ c,
    const long long* __restrict__ hk, const int* __restrict__ hv,
    const int* __restrict__ nactp, int* __restrict__ pslot, int* __restrict__ cnt,
    int* __restrict__ ocnt, int* __restrict__ olist,
    int D, int H, int Wd)
{
  constexpr int K3 = K*K*K, R = K/2, CTR = K3/2;
  const int site = blockIdx.x * 4 + (threadIdx.x >> 6);
  const int lane = threadIdx.x & 63;
  const int nact = *nactp;
  if (site >= NV) return;
  if (site >= nact) { if (lane == 0) cnt[site] = 0; return; }
  const int b = c[site*4+0], d = c[site*4+1], hc = c[site*4+2], w = c[site*4+3];
  int base = 0;
  for (int o0 = 0; o0 < K3; o0 += 64) {
    const int o = o0 + lane;
    int j = -1;
    if (o < K3 && o != CTR) {
      const int dz = o/(K*K) - R, dy = (o/K)%K - R, dx = o%K - R;
      const int nd = d+dz, nh = hc+dy, nw = w+dx;
      if (nd >= 0 && nd < D && nh >= 0 && nh < H && nw >= 0 && nw < Wd) {
        const long long key = (((long long)b*D + nd)*H + nh)*(long long)Wd + nw;
        unsigned hs = hashk(key);
        while (true) {
          const long long kk = hk[hs];
          if (kk == -1LL) break;
          if (kk == key) { j = hv[hs]; break; }
          hs = (hs + 1) & HMASK;
        }
      }
    }
    const unsigned long long m = __ballot(j >= 0);
    if (j >= 0) {
      const int pos = __popcll(m & ((1ull << lane) - 1ull));
      const int p = atomicAdd(&ocnt[o], 1);
      int tag = -1;
      if (p < MAXP) { olist[o * MAXP + p] = (site << 12) | j; tag = (o << 8) | p; }
      pslot[site * MAXE + base + pos] = tag;
    }
    base += __popcll(m);
  }
  if (lane == 0) cnt[site] = base;
}

// ---------------- exclusive scan of per-offset hit counts -> compact slot bases ----------------
__global__ __launch_bounds__(512) void k_oscan(const int* __restrict__ ocnt,
    int* __restrict__ obase)
{
  __shared__ int s[512];
  const int t = threadIdx.x;
  const int v = (t < K3MAX) ? min(ocnt[t], MAXP) : 0;
  s[t] = v;
  __syncthreads();
  for (int d = 1; d < 512; d <<= 1) {
    const int x = (t >= d) ? s[t - d] : 0;
    __syncthreads();
    s[t] += x;
    __syncthreads();
  }
  if (t < K3MAX) obase[t] = s[t] - v;
}

// ---------------- dense center GEMM: out = f @ Wc (2-D tiled, float4 W) ----------------
// Inactive rows of f are exactly 0, so unconditional compute writes 0 there.
template<int CIN, int COUT>
__global__ __launch_bounds__(256) void k_gemm(const float* __restrict__ f,
    const float* __restrict__ Wc, float* __restrict__ out)
{
  constexpr int TN   = (COUT < 128) ? COUT : 128;  // cols per block
  constexpr int TNQ  = TN / 4;                     // col-quads per block
  constexpr int ROWS = 256 / TNQ;                  // rows per block (8 or 16)
  constexpr int NCB  = COUT / TN;                  // column blocks
  __shared__ float as[ROWS][CIN + 1];
  const int rb = blockIdx.x / NCB;
  const int cb = blockIdx.x - rb * NCB;
  const int row0 = rb * ROWS;
  const int tid = threadIdx.x;
  const int r  = tid / TNQ;
  const int q  = tid - r * TNQ;
  const int col = cb * TN + q * 4;

  #pragma unroll
  for (int rr = 0; rr < ROWS; ++rr)
    for (int k = tid; k < CIN; k += 256)
      as[rr][k] = f[(row0 + rr) * CIN + k];
  __syncthreads();

  float4 acc; acc.x = 0.f; acc.y = 0.f; acc.z = 0.f; acc.w = 0.f;
  const float* __restrict__ wp = Wc + col;
  #pragma unroll 8
  for (int k = 0; k < CIN; ++k) {
    const float av = as[r][k];
    const float4 wv = *(const float4*)&wp[(size_t)k * COUT];
    acc.x = fmaf(av, wv.x, acc.x);
    acc.y = fmaf(av, wv.y, acc.y);
    acc.z = fmaf(av, wv.z, acc.z);
    acc.w = fmaf(av, wv.w, acc.w);
  }
  *(float4*)&out[(size_t)(row0 + r) * COUT + col] = acc;
}

// ---------------- phase 1: per-(offset, k-slice) partial GEMM, float4 W stream ----------------
template<int CIN, int COUT>
__global__ __launch_bounds__(256) void k_pgemm(const float* __restrict__ f,
    const float* __restrict__ Wall, float* __restrict__ P,
    const int* __restrict__ ocnt, const int* __restrict__ obase,
    const int* __restrict__ olist)
{
  constexpr int KSUB = 32;
  constexpr int CPW  = COUT / 4;
  constexpr int NKQ  = (256 / CPW) < 1 ? 1 : (256 / CPW);
  constexpr int KS_TOT = (CIN + KSUB - 1) / KSUB;
  constexpr int NKB  = (KS_TOT + NKQ - 1) / NKQ;
  constexpr int KLEN = (CIN >= KSUB) ? KSUB : CIN;
  constexpr int KBLK = (NKQ*KSUB < CIN) ? NKQ*KSUB : CIN;
  constexpr int HB   = 8;
  constexpr int SLOTCAP = (40*1024*1024) / (KS_TOT*COUT*4);

  const int o  = blockIdx.x / NKB;
  const int kb = blockIdx.x - o*NKB;
  int m = ocnt[o];
  if (m == 0) return;
  if (m > MAXP) m = MAXP;
  const int sbase = obase[o];
  const int tid = threadIdx.x;
  const int kq  = tid / CPW;
  const int cq  = tid - kq*CPW;
  const int ks  = kb*NKQ + kq;
  const bool act = (kq < NKQ) && (ks < KS_TOT);
  const int kbase = kb * (NKQ*KSUB);
  const int k0 = ks * KSUB;
  const int c  = cq * 4;
  const int kblk_eff = (CIN - kbase < KBLK) ? (CIN - kbase) : KBLK;
  __shared__ float fs[HB][KBLK];
  const float* __restrict__ Wo = Wall + (size_t)o * (CIN*COUT);

  for (int p0 = 0; p0 < m; p0 += HB) {
    const int hb = min(HB, m - p0);
    __syncthreads();
    for (int idx = tid; idx < hb*kblk_eff; idx += 256) {
      const int h = idx / kblk_eff, k = idx - h*kblk_eff;
      const int j = olist[o*MAXP + p0 + h] & 0xFFF;
      fs[h][k] = f[j*CIN + kbase + k];
    }
    __syncthreads();
    if (act) {
      float4 acc[HB];
      #pragma unroll
      for (int h = 0; h < HB; ++h) { acc[h].x=0.f; acc[h].y=0.f; acc[h].z=0.f; acc[h].w=0.f; }
      #pragma unroll
      for (int k = 0; k < KLEN; ++k) {
        const float4 wv = *(const float4*)&Wo[(size_t)(k0+k)*COUT + c];
        const int lk = kq*KSUB + k;
        #pragma unroll
        for (int h = 0; h < HB; ++h) {
          const float fv = fs[h][lk];
          acc[h].x = fmaf(fv, wv.x, acc[h].x);
          acc[h].y = fmaf(fv, wv.y, acc[h].y);
          acc[h].z = fmaf(fv, wv.z, acc[h].z);
          acc[h].w = fmaf(fv, wv.w, acc[h].w);
        }
      }
      for (int h = 0; h < hb; ++h) {
        const int slot = sbase + p0 + h;
        if (slot < SLOTCAP)
          *(float4*)&P[((size_t)slot*KS_TOT + ks)*COUT + c] = acc[h];
      }
    }
  }
}

// ---------------- phase 2: per-site deterministic sum of partials ----------------
template<int COUT, int KS>
__global__ __launch_bounds__(256) void k_psum(float* __restrict__ out,
    const float* __restrict__ P, const int* __restrict__ pslot,
    const int* __restrict__ obase, const int* __restrict__ cnt,
    const int* __restrict__ nactp)
{
  constexpr int SLOTCAP = (40*1024*1024) / (KS*COUT*4);
  const int idx = blockIdx.x * 256 + threadIdx.x;
  const int i = idx / COUT;
  if (i >= *nactp) return;
  const int n = cnt[i];
  if (n == 0) return;
  const int cc = idx - i * COUT;
  float acc = 0.f;
  for (int h = 0; h < n; ++h) {
    const int e = pslot[i * MAXE + h];
    if (e < 0) continue;
    const int slot = obase[e >> 8] + (e & 0xFF);
    if (slot >= SLOTCAP) continue;
    #pragma unroll
    for (int ks = 0; ks < KS; ++ks)
      acc += P[((size_t)slot * KS + ks) * COUT + cc];
  }
  out[idx] += acc;
}

// ---------------- BN stats -> scale/shift ----------------
template<int COUT>
__global__ __launch_bounds__(256) void k_bnstats(const float* __restrict__ x,
    const float* __restrict__ g, const float* __restrict__ b,
    float* __restrict__ scale, float* __restrict__ shift, const int* __restrict__ nactp)
{
  const int c = blockIdx.x;
  const int tid = threadIdx.x;
  double s1 = 0.0, s2 = 0.0;
  for (int r = tid; r < NV; r += 256) {
    const double v = (double)x[r * COUT + c];
    s1 += v; s2 += v * v;
  }
  __shared__ double r1[256], r2[256];
  r1[tid] = s1; r2[tid] = s2;
  __syncthreads();
  for (int off = 128; off > 0; off >>= 1) {
    if (tid < off) { r1[tid] += r1[tid + off]; r2[tid] += r2[tid + off]; }
    __syncthreads();
  }
  if (tid == 0) {
    const double n = (double)(*nactp);
    const double mu = r1[0] / n;
    double var = r2[0] / n - mu * mu;
    if (var < 0.0) var = 0.0;
    const double sc = (double)g[c] / sqrt(var + 1e-4);
    scale[c] = (float)sc;
    shift[c] = (float)((double)b[c] - mu * sc);
  }
}

// ---------------- BN apply + ReLU (in place) ----------------
template<int COUT>
__global__ __launch_bounds__(256) void k_bnrelu(float* __restrict__ x,
    const float* __restrict__ scale, const float* __restrict__ shift,
    const int* __restrict__ nactp)
{
  const int idx = blockIdx.x * 256 + threadIdx.x;
  if (idx >= NV * COUT) return;
  const int i = idx / COUT, c = idx % COUT;
  float v = 0.f;
  if (i < *nactp) {
    const float y = fmaf(x[idx], scale[c], shift[c]);
    v = (y > 0.f) ? y : 0.f;
  }
  x[idx] = v;
}

// ---------------- pooling ----------------
__global__ __launch_bounds__(256) void k_poolkey(const int* __restrict__ c,
    long long* __restrict__ pk, const int* __restrict__ nactp,
    int sd, int sh, int sw, int oD, int oH, int oW)
{
  const int i = blockIdx.x * 256 + threadIdx.x;
  if (i >= NV) return;
  if (i < *nactp) {
    const int b = c[i*4+0];
    const int d = c[i*4+1] / sd, h = c[i*4+2] / sh, w = c[i*4+3] / sw;
    pk[i] = (((long long)b*oD + d)*oH + h)*(long long)oW + w;
  } else pk[i] = BIGK;
}

__global__ __launch_bounds__(1024) void k_sortcompact(const long long* __restrict__ pk,
    int* __restrict__ cNew, int* __restrict__ map, int* __restrict__ nactOut,
    int D, int H, int Wd)
{
  __shared__ long long sk[NV];
  __shared__ int si[NV];
  __shared__ int sc[NV];
  __shared__ int s2[NV];
  const int tid = threadIdx.x;
  for (int e = 0; e < 2; ++e) { const int t = tid + e*1024; sk[t] = pk[t]; si[t] = t; }
  __syncthreads();
  for (int k = 2; k <= NV; k <<= 1)
    for (int j = k >> 1; j > 0; j >>= 1) {
      for (int e = 0; e < 2; ++e) {
        const int i = tid + e*1024;
        const int ixj = i ^ j;
        if (ixj > i) {
          const bool up = ((i & k) == 0);
          const long long a = sk[i], bb = sk[ixj];
          const bool sw = up ? (a > bb) : (a < bb);
          if (sw) { sk[i] = bb; sk[ixj] = a; const int t2 = si[i]; si[i] = si[ixj]; si[ixj] = t2; }
        }
      }
      __syncthreads();
    }
  for (int e = 0; e < 2; ++e) {
    const int t = tid + e*1024;
    sc[t] = (sk[t] != BIGK && (t == 0 || sk[t] != sk[t-1])) ? 1 : 0;
  }
  __syncthreads();
  for (int d2 = 1; d2 < NV; d2 <<= 1) {
    for (int e = 0; e < 2; ++e) { const int t = tid + e*1024; s2[t] = sc[t] + ((t >= d2) ? sc[t - d2] : 0); }
    __syncthreads();
    for (int e = 0; e < 2; ++e) { const int t = tid + e*1024; sc[t] = s2[t]; }
    __syncthreads();
  }
  for (int e = 0; e < 2; ++e) {
    const int t = tid + e*1024;
    const long long key = sk[t];
    if (key != BIGK) {
      const int g = sc[t] - 1;
      map[si[t]] = g;
      if (t == 0 || sk[t-1] != key) {
        const int w = (int)(key % Wd);
        long long r = key / Wd;
        const int h = (int)(r % H); r /= H;
        const int d = (int)(r % D);
        const int b = (int)(r / D);
        cNew[g*4+0] = b; cNew[g*4+1] = d; cNew[g*4+2] = h; cNew[g*4+3] = w;
      }
    }
  }
  if (tid == 0) *nactOut = sc[NV-1];
}

__global__ __launch_bounds__(256) void k_zero(float* __restrict__ x, int n) {
  const int idx = blockIdx.x * 256 + threadIdx.x;
  if (idx < n) x[idx] = 0.f;
}

template<int C>
__global__ __launch_bounds__(256) void k_pscatter(const float* __restrict__ src,
    float* __restrict__ dst, const int* __restrict__ map, const int* __restrict__ nactp)
{
  const int idx = blockIdx.x * 256 + threadIdx.x;
  const int i = idx / C;
  if (i >= *nactp) return;
  atomicMax((unsigned*)&dst[map[i] * C + (idx % C)], __float_as_uint(src[idx]));
}

// ---------------- final dense scatter ----------------
__global__ __launch_bounds__(256) void k_out(const float* __restrict__ f,
    const int* __restrict__ c, float* __restrict__ out, const int* __restrict__ nactp)
{
  const int idx = blockIdx.x * 256 + threadIdx.x;
  const int i = idx >> 9, ch = idx & 511;
  if (i >= *nactp) return;
  const int b = c[i*4+0], d = c[i*4+1], h = c[i*4+2], w = c[i*4+3];
  out[ (((b*512 + ch)*2 + d)*111 + h)*98 + w ] = f[idx];
}

// ---------------- host orchestration ----------------
template<int K, int CIN, int C>
static void run_stage(hipStream_t stream, int s,
    const float* Wa, const float* Ga, const float* Ba,
    const float* Wb, const float* Gb, const float* Bb,
    float* fX, float* fY, int* cX, int* cY,
    int D, int H, int W, int pd, int ph, int pw, int oD, int oH, int oW,
    long long* hk, int* hv, long long* pkey, int* pslot, int* cnt, int* map,
    int* nact, float* scale, float* shift,
    int* ocnt, int* obase, int* olist, float* P)
{
  constexpr int K3 = K*K*K;
  constexpr int CTR = K3/2;
  constexpr int CPW = C / 4;
  constexpr int NKQ = (256 / CPW) < 1 ? 1 : (256 / CPW);
  constexpr int KS1 = (CIN + 31) / 32;
  constexpr int KS2 = (C + 31) / 32;
  constexpr int NKB1 = (KS1 + NKQ - 1) / NKQ;
  constexpr int NKB2 = (KS2 + NKQ - 1) / NKQ;
  // k_gemm grids
  constexpr int TN1   = (C < 128) ? C : 128;
  constexpr int ROWS1 = 256 / (TN1 / 4);
  constexpr int G1    = (NV / ROWS1) * (C / TN1);
  const int* na = nact + s;
  k_hclear<<<HSIZE/256, 256, 0, stream>>>(hk, ocnt);
  k_hinsert<<<NV/256, 256, 0, stream>>>(cX, hk, hv, na, D, H, W);
  k_hits<K><<<NV/4, 256, 0, stream>>>(cX, hk, hv, na, pslot, cnt, ocnt, olist, D, H, W);
  k_oscan<<<1, 512, 0, stream>>>(ocnt, obase);

  k_gemm<CIN, C><<<G1, 256, 0, stream>>>(fX, Wa + (size_t)CTR*CIN*C, fY);
  k_pgemm<CIN, C><<<K3*NKB1, 256, 0, stream>>>(fX, Wa, P, ocnt, obase, olist);
  k_psum<C, KS1><<<NV*C/256, 256, 0, stream>>>(fY, P, pslot, obase, cnt, na);
  k_bnstats<C><<<C, 256, 0, stream>>>(fY, Ga, Ba, scale, shift, na);
  k_bnrelu<C><<<NV*C/256, 256, 0, stream>>>(fY, scale, shift, na);

  k_gemm<C, C><<<G1, 256, 0, stream>>>(fY, Wb + (size_t)CTR*C*C, fX);
  k_pgemm<C, C><<<K3*NKB2, 256, 0, stream>>>(fY, Wb, P, ocnt, obase, olist);
  k_psum<C, KS2><<<NV*C/256, 256, 0, stream>>>(fX, P, pslot, obase, cnt, na);
  k_bnstats<C><<<C, 256, 0, stream>>>(fX, Gb, Bb, scale, shift, na);
  k_bnrelu<C><<<NV*C/256, 256, 0, stream>>>(fX, scale, shift, na);

  k_poolkey<<<NV/256, 256, 0, stream>>>(cX, pkey, na, pd, ph, pw, oD, oH, oW);
  k_sortcompact<<<1, 1024, 0, stream>>>(pkey, cY, map, nact + s + 1, oD, oH, oW);
  k_zero<<<NV*C/256, 256, 0, stream>>>(fY, NV*C);
  k_pscatter<C><<<NV*C/256, 256, 0, stream>>>(fX, fY, map, na);
}

extern "C" void kernel_launch(void* const* d_in, const int* in_sizes, int n_in,
                              void* d_out, int out_size, void* d_ws, size_t ws_size,
                              hipStream_t stream)
{
  const float* vf    = (const float*)d_in[0];
  const int*   coors = (const int*)d_in[1];
  const float *Wl[10], *Gl[10], *Bl[10];
  for (int i = 0; i < 10; ++i) {
    Wl[i] = (const float*)d_in[3 + 3*i];
    Gl[i] = (const float*)d_in[4 + 3*i];
    Bl[i] = (const float*)d_in[5 + 3*i];
  }

  char* p = (char*)d_ws;
  auto alloc = [&](size_t bytes) { char* q = p; p += (bytes + 255) & ~(size_t)255; return q; };
  float*     fB    = (float*)    alloc((size_t)NV*512*4);
  long long* hk    = (long long*)alloc((size_t)HSIZE*8);
  long long* pkey  = (long long*)alloc((size_t)NV*8);
  int*       hv    = (int*)      alloc((size_t)HSIZE*4);
  int*       cA    = (int*)      alloc((size_t)NV*4*4);
  int*       cB    = (int*)      alloc((size_t)NV*4*4);
  int*       pslot = (int*)      alloc((size_t)NV*MAXE*4);
  int*       cnt   = (int*)      alloc((size_t)NV*4);
  int*       map   = (int*)      alloc((size_t)NV*4);
  int*       nact  = (int*)      alloc(8*4);
  float*     scale = (float*)    alloc(512*4);
  float*     shift = (float*)    alloc(512*4);
  int*       ocnt  = (int*)      alloc((size_t)K3MAX*4);
  int*       obase = (int*)      alloc((size_t)K3MAX*4);

  // scratch aliased into d_out (89 MB); all dead before the final memset
  float* fA    = (float*)d_out;                                   // 4 MB
  float* P     = (float*)((char*)d_out + (size_t)8*1024*1024);    // 40 MB budget (SLOTCAP-guarded)
  int*   olist = (int*)  ((char*)d_out + (size_t)48*1024*1024);   // 343*256*4 = 351 KB

  k_init<<<NV/256, 256, 0, stream>>>(vf, coors, cA, fA, nact);

  run_stage<7, 1, 64>  (stream, 0, Wl[0],Gl[0],Bl[0], Wl[1],Gl[1],Bl[1],
    fA, fB, cA, cB, 216, 7992, 7056, 3, 3, 3, 72, 2664, 2352,
    hk, hv, pkey, pslot, cnt, map, nact, scale, shift, ocnt, obase, olist, P);
  run_stage<7, 64, 128>(stream, 1, Wl[2],Gl[2],Bl[2], Wl[3],Gl[3],Bl[3],
    fB, fA, cB, cA, 72, 2664, 2352, 3, 3, 3, 24, 888, 784,
    hk, hv, pkey, pslot, cnt, map, nact, scale, shift, ocnt, obase, olist, P);
  run_stage<5, 128, 256>(stream, 2, Wl[4],Gl[4],Bl[4], Wl[5],Gl[5],Bl[5],
    fA, fB, cA, cB, 24, 888, 784, 3, 2, 2, 8, 444, 392,
    hk, hv, pkey, pslot, cnt, map, nact, scale, shift, ocnt, obase, olist, P);
  run_stage<3, 256, 384>(stream, 3, Wl[6],Gl[6],Bl[6], Wl[7],Gl[7],Bl[7],
    fB, fA, cB, cA, 8, 444, 392, 2, 2, 2, 4, 222, 196,
    hk, hv, pkey, pslot, cnt, map, nact, scale, shift, ocnt, obase, olist, P);
  run_stage<3, 384, 512>(stream, 4, Wl[8],Gl[8],Bl[8], Wl[9],Gl[9],Bl[9],
    fA, fB, cA, cB, 4, 222, 196, 2, 2, 2, 2, 111, 98,
    hk, hv, pkey, pslot, cnt, map, nact, scale, shift, ocnt, obase, olist, P);

  hipMemsetAsync(d_out, 0, (size_t)out_size * sizeof(float), stream);
  k_out<<<NV*512/256, 256, 0, stream>>>(fB, cB, (float*)d_out, nact + 5);
}

// Round 6
// 796.609 us; speedup vs baseline: 3.4798x; 1.0738x over previous
//
#include <hip/hip_runtime.h>
#include <climits>
#include <cstdint>

#define NV    2048
#define MAXE  344
#define HSIZE 8192
#define HMASK 8191
#define BIGK  LLONG_MAX
#define K3MAX 343
#define MAXP  256

__device__ __forceinline__ unsigned hashk(long long k) {
  unsigned long long x = (unsigned long long)k * 0x9E3779B97F4A7C15ull;
  return (unsigned)(x >> 51) & HMASK;
}

// ---------------- init ----------------
__global__ __launch_bounds__(256) void k_init(const float* __restrict__ vf,
    const int* __restrict__ coors, int* __restrict__ cA, float* __restrict__ fA,
    int* __restrict__ nact)
{
  int i = blockIdx.x * 256 + threadIdx.x;
  if (i == 0) nact[0] = NV;
  if (i >= NV) return;
  cA[i*4+0] = coors[i*4+0];
  cA[i*4+1] = coors[i*4+1];
  cA[i*4+2] = coors[i*4+2];
  cA[i*4+3] = coors[i*4+3];
  fA[i] = vf[i];
}

// ---------------- hash ----------------
__global__ __launch_bounds__(256) void k_hclear(long long* __restrict__ hk,
    int* __restrict__ ocnt)
{
  int i = blockIdx.x * 256 + threadIdx.x;
  if (i < HSIZE) hk[i] = -1LL;
  if (i < K3MAX) ocnt[i] = 0;
}

__global__ __launch_bounds__(256) void k_hinsert(const int* __restrict__ c,
    long long* __restrict__ hk, int* __restrict__ hv, const int* __restrict__ nactp,
    int D, int H, int Wd)
{
  int i = blockIdx.x * 256 + threadIdx.x;
  if (i >= NV || i >= *nactp) return;
  long long key = (((long long)c[i*4+0]*D + c[i*4+1])*H + c[i*4+2])*(long long)Wd + c[i*4+3];
  unsigned h = hashk(key);
  while (true) {
    unsigned long long old = atomicCAS((unsigned long long*)&hk[h], ~0ull, (unsigned long long)key);
    if (old == ~0ull) { hv[h] = i; break; }
    h = (h + 1) & HMASK;
  }
}

// ---------------- neighbor hit lists (one wave per site), grouped by offset ----------------
template<int K>
__global__ __launch_bounds__(256) void k_hits(const int* __restrict__ c,
    const long long* __restrict__ hk, const int* __restrict__ hv,
    const int* __restrict__ nactp, int* __restrict__ pslot, int* __restrict__ cnt,
    int* __restrict__ ocnt, int* __restrict__ olist,
    int D, int H, int Wd)
{
  constexpr int K3 = K*K*K, R = K/2, CTR = K3/2;
  const int site = blockIdx.x * 4 + (threadIdx.x >> 6);
  const int lane = threadIdx.x & 63;
  const int nact = *nactp;
  if (site >= NV) return;
  if (site >= nact) { if (lane == 0) cnt[site] = 0; return; }
  const int b = c[site*4+0], d = c[site*4+1], hc = c[site*4+2], w = c[site*4+3];
  int base = 0;
  for (int o0 = 0; o0 < K3; o0 += 64) {
    const int o = o0 + lane;
    int j = -1;
    if (o < K3 && o != CTR) {
      const int dz = o/(K*K) - R, dy = (o/K)%K - R, dx = o%K - R;
      const int nd = d+dz, nh = hc+dy, nw = w+dx;
      if (nd >= 0 && nd < D && nh >= 0 && nh < H && nw >= 0 && nw < Wd) {
        const long long key = (((long long)b*D + nd)*H + nh)*(long long)Wd + nw;
        unsigned hs = hashk(key);
        while (true) {
          const long long kk = hk[hs];
          if (kk == -1LL) break;
          if (kk == key) { j = hv[hs]; break; }
          hs = (hs + 1) & HMASK;
        }
      }
    }
    const unsigned long long m = __ballot(j >= 0);
    if (j >= 0) {
      const int pos = __popcll(m & ((1ull << lane) - 1ull));
      const int p = atomicAdd(&ocnt[o], 1);
      int tag = -1;
      if (p < MAXP) { olist[o * MAXP + p] = (site << 12) | j; tag = (o << 8) | p; }
      pslot[site * MAXE + base + pos] = tag;
    }
    base += __popcll(m);
  }
  if (lane == 0) cnt[site] = base;
}

// ---------------- exclusive scan of per-offset hit counts -> compact slot bases ----------------
__global__ __launch_bounds__(512) void k_oscan(const int* __restrict__ ocnt,
    int* __restrict__ obase)
{
  __shared__ int s[512];
  const int t = threadIdx.x;
  const int v = (t < K3MAX) ? min(ocnt[t], MAXP) : 0;
  s[t] = v;
  __syncthreads();
  for (int d = 1; d < 512; d <<= 1) {
    const int x = (t >= d) ? s[t - d] : 0;
    __syncthreads();
    s[t] += x;
    __syncthreads();
  }
  if (t < K3MAX) obase[t] = s[t] - v;
}

// ---------------- center GEMM, CIN==1: outer product ----------------
template<int COUT>
__global__ __launch_bounds__(256) void k_gemm1(const float* __restrict__ f,
    const float* __restrict__ Wc, float* __restrict__ out)
{
  const int idx = blockIdx.x * 256 + threadIdx.x;
  if (idx >= NV * COUT) return;
  const int i = idx / COUT, c = idx - i * COUT;
  out[idx] = f[i] * Wc[c];
}

// ---------------- dense center GEMM: LDS-tiled, reg-prefetch double buffer ----------------
// Inactive rows of f are exactly 0, so unconditional compute writes 0 there.
template<int CIN, int COUT>
__global__ __launch_bounds__(256) void k_gemm(const float* __restrict__ f,
    const float* __restrict__ Wc, float* __restrict__ out)
{
  constexpr int BN = (COUT < 128) ? COUT : 128;
  constexpr int NQ = BN / 4;        // col-quads per block (16 or 32)
  constexpr int TY = 256 / NQ;      // row groups (16 or 8)
  constexpr int BM = 32;
  constexpr int MR = BM / TY;       // rows per thread (2 or 4)
  constexpr int KT = 32;
  constexpr int NT = CIN / KT;
  constexpr int NCB = COUT / BN;
  constexpr int WLPT = (KT * NQ) / 256;  // W float4 loads/thread (2 or 4)
  __shared__ float as[BM][KT + 1];
  __shared__ float ws[KT][BN];

  const int rb = blockIdx.x / NCB;
  const int cb = blockIdx.x - rb * NCB;
  const int row0 = rb * BM;
  const int col0 = cb * BN;
  const int tid = threadIdx.x;
  const int cq = tid % NQ;
  const int ty = tid / NQ;
  const int la_r = tid >> 3;        // A loader: row, 8 quads/row (KT=32)
  const int la_q = tid & 7;

  const float* __restrict__ fA = f + (size_t)(row0 + la_r) * CIN + la_q * 4;
  const float* __restrict__ fW = Wc + col0;

  float4 aP, wP[WLPT];
  aP = *(const float4*)&fA[0];
  #pragma unroll
  for (int i = 0; i < WLPT; ++i) {
    const int idx = tid + i*256, k = idx / NQ, q = idx - k*NQ;
    wP[i] = *(const float4*)&fW[(size_t)k * COUT + q*4];
  }

  float4 acc[MR];
  #pragma unroll
  for (int i = 0; i < MR; ++i) { acc[i].x=0.f; acc[i].y=0.f; acc[i].z=0.f; acc[i].w=0.f; }

  for (int t = 0; t < NT; ++t) {
    as[la_r][la_q*4+0] = aP.x;
    as[la_r][la_q*4+1] = aP.y;
    as[la_r][la_q*4+2] = aP.z;
    as[la_r][la_q*4+3] = aP.w;
    #pragma unroll
    for (int i = 0; i < WLPT; ++i) {
      const int idx = tid + i*256, k = idx / NQ, q = idx - k*NQ;
      *(float4*)&ws[k][q*4] = wP[i];
    }
    __syncthreads();
    if (t + 1 < NT) {
      const int k0 = (t + 1) * KT;
      aP = *(const float4*)&fA[k0];
      #pragma unroll
      for (int i = 0; i < WLPT; ++i) {
        const int idx = tid + i*256, k = idx / NQ, q = idx - k*NQ;
        wP[i] = *(const float4*)&fW[(size_t)(k0 + k) * COUT + q*4];
      }
    }
    #pragma unroll
    for (int k = 0; k < KT; ++k) {
      const float4 wv = *(const float4*)&ws[k][cq*4];
      #pragma unroll
      for (int i = 0; i < MR; ++i) {
        const float av = as[ty*MR + i][k];
        acc[i].x = fmaf(av, wv.x, acc[i].x);
        acc[i].y = fmaf(av, wv.y, acc[i].y);
        acc[i].z = fmaf(av, wv.z, acc[i].z);
        acc[i].w = fmaf(av, wv.w, acc[i].w);
      }
    }
    __syncthreads();
  }
  #pragma unroll
  for (int i = 0; i < MR; ++i)
    *(float4*)&out[(size_t)(row0 + ty*MR + i) * COUT + col0 + cq*4] = acc[i];
}

// ---------------- phase 1: per-(offset, k-slice) partial GEMM, float4 W stream ----------------
template<int CIN, int COUT>
__global__ __launch_bounds__(256) void k_pgemm(const float* __restrict__ f,
    const float* __restrict__ Wall, float* __restrict__ P,
    const int* __restrict__ ocnt, const int* __restrict__ obase,
    const int* __restrict__ olist)
{
  constexpr int KSUB = 32;
  constexpr int CPW  = COUT / 4;
  constexpr int NKQ  = (256 / CPW) < 1 ? 1 : (256 / CPW);
  constexpr int KS_TOT = (CIN + KSUB - 1) / KSUB;
  constexpr int NKB  = (KS_TOT + NKQ - 1) / NKQ;
  constexpr int KLEN = (CIN >= KSUB) ? KSUB : CIN;
  constexpr int KBLK = (NKQ*KSUB < CIN) ? NKQ*KSUB : CIN;
  constexpr int HB   = 8;
  constexpr int SLOTCAP = (40*1024*1024) / (KS_TOT*COUT*4);

  const int o  = blockIdx.x / NKB;
  const int kb = blockIdx.x - o*NKB;
  int m = ocnt[o];
  if (m == 0) return;
  if (m > MAXP) m = MAXP;
  const int sbase = obase[o];
  const int tid = threadIdx.x;
  const int kq  = tid / CPW;
  const int cq  = tid - kq*CPW;
  const int ks  = kb*NKQ + kq;
  const bool act = (kq < NKQ) && (ks < KS_TOT);
  const int kbase = kb * (NKQ*KSUB);
  const int k0 = ks * KSUB;
  const int c  = cq * 4;
  const int kblk_eff = (CIN - kbase < KBLK) ? (CIN - kbase) : KBLK;
  __shared__ float fs[HB][KBLK];
  const float* __restrict__ Wo = Wall + (size_t)o * (CIN*COUT);

  for (int p0 = 0; p0 < m; p0 += HB) {
    const int hb = min(HB, m - p0);
    __syncthreads();
    for (int idx = tid; idx < hb*kblk_eff; idx += 256) {
      const int h = idx / kblk_eff, k = idx - h*kblk_eff;
      const int j = olist[o*MAXP + p0 + h] & 0xFFF;
      fs[h][k] = f[j*CIN + kbase + k];
    }
    __syncthreads();
    if (act) {
      float4 acc[HB];
      #pragma unroll
      for (int h = 0; h < HB; ++h) { acc[h].x=0.f; acc[h].y=0.f; acc[h].z=0.f; acc[h].w=0.f; }
      #pragma unroll
      for (int k = 0; k < KLEN; ++k) {
        const float4 wv = *(const float4*)&Wo[(size_t)(k0+k)*COUT + c];
        const int lk = kq*KSUB + k;
        #pragma unroll
        for (int h = 0; h < HB; ++h) {
          const float fv = fs[h][lk];
          acc[h].x = fmaf(fv, wv.x, acc[h].x);
          acc[h].y = fmaf(fv, wv.y, acc[h].y);
          acc[h].z = fmaf(fv, wv.z, acc[h].z);
          acc[h].w = fmaf(fv, wv.w, acc[h].w);
        }
      }
      for (int h = 0; h < hb; ++h) {
        const int slot = sbase + p0 + h;
        if (slot < SLOTCAP)
          *(float4*)&P[((size_t)slot*KS_TOT + ks)*COUT + c] = acc[h];
      }
    }
  }
}

// ---------------- phase 2: per-site deterministic sum of partials ----------------
template<int COUT, int KS>
__global__ __launch_bounds__(256) void k_psum(float* __restrict__ out,
    const float* __restrict__ P, const int* __restrict__ pslot,
    const int* __restrict__ obase, const int* __restrict__ cnt,
    const int* __restrict__ nactp)
{
  constexpr int SLOTCAP = (40*1024*1024) / (KS*COUT*4);
  const int idx = blockIdx.x * 256 + threadIdx.x;
  const int i = idx / COUT;
  if (i >= *nactp) return;
  const int n = cnt[i];
  if (n == 0) return;
  const int cc = idx - i * COUT;
  float acc = 0.f;
  for (int h = 0; h < n; ++h) {
    const int e = pslot[i * MAXE + h];
    if (e < 0) continue;
    const int slot = obase[e >> 8] + (e & 0xFF);
    if (slot >= SLOTCAP) continue;
    #pragma unroll
    for (int ks = 0; ks < KS; ++ks)
      acc += P[((size_t)slot * KS + ks) * COUT + cc];
  }
  out[idx] += acc;
}

// ---------------- BN stats -> scale/shift ----------------
template<int COUT>
__global__ __launch_bounds__(256) void k_bnstats(const float* __restrict__ x,
    const float* __restrict__ g, const float* __restrict__ b,
    float* __restrict__ scale, float* __restrict__ shift, const int* __restrict__ nactp)
{
  const int c = blockIdx.x;
  const int tid = threadIdx.x;
  double s1 = 0.0, s2 = 0.0;
  for (int r = tid; r < NV; r += 256) {
    const double v = (double)x[r * COUT + c];
    s1 += v; s2 += v * v;
  }
  __shared__ double r1[256], r2[256];
  r1[tid] = s1; r2[tid] = s2;
  __syncthreads();
  for (int off = 128; off > 0; off >>= 1) {
    if (tid < off) { r1[tid] += r1[tid + off]; r2[tid] += r2[tid + off]; }
    __syncthreads();
  }
  if (tid == 0) {
    const double n = (double)(*nactp);
    const double mu = r1[0] / n;
    double var = r2[0] / n - mu * mu;
    if (var < 0.0) var = 0.0;
    const double sc = (double)g[c] / sqrt(var + 1e-4);
    scale[c] = (float)sc;
    shift[c] = (float)((double)b[c] - mu * sc);
  }
}

// ---------------- BN apply + ReLU (in place) ----------------
template<int COUT>
__global__ __launch_bounds__(256) void k_bnrelu(float* __restrict__ x,
    const float* __restrict__ scale, const float* __restrict__ shift,
    const int* __restrict__ nactp)
{
  const int idx = blockIdx.x * 256 + threadIdx.x;
  if (idx >= NV * COUT) return;
  const int i = idx / COUT, c = idx % COUT;
  float v = 0.f;
  if (i < *nactp) {
    const float y = fmaf(x[idx], scale[c], shift[c]);
    v = (y > 0.f) ? y : 0.f;
  }
  x[idx] = v;
}

// ---------------- pooling ----------------
__global__ __launch_bounds__(256) void k_poolkey(const int* __restrict__ c,
    long long* __restrict__ pk, const int* __restrict__ nactp,
    int sd, int sh, int sw, int oD, int oH, int oW)
{
  const int i = blockIdx.x * 256 + threadIdx.x;
  if (i >= NV) return;
  if (i < *nactp) {
    const int b = c[i*4+0];
    const int d = c[i*4+1] / sd, h = c[i*4+2] / sh, w = c[i*4+3] / sw;
    pk[i] = (((long long)b*oD + d)*oH + h)*(long long)oW + w;
  } else pk[i] = BIGK;
}

__global__ __launch_bounds__(1024) void k_sortcompact(const long long* __restrict__ pk,
    int* __restrict__ cNew, int* __restrict__ map, int* __restrict__ nactOut,
    int D, int H, int Wd)
{
  __shared__ long long sk[NV];
  __shared__ int si[NV];
  __shared__ int sc[NV];
  __shared__ int s2[NV];
  const int tid = threadIdx.x;
  for (int e = 0; e < 2; ++e) { const int t = tid + e*1024; sk[t] = pk[t]; si[t] = t; }
  __syncthreads();
  for (int k = 2; k <= NV; k <<= 1)
    for (int j = k >> 1; j > 0; j >>= 1) {
      for (int e = 0; e < 2; ++e) {
        const int i = tid + e*1024;
        const int ixj = i ^ j;
        if (ixj > i) {
          const bool up = ((i & k) == 0);
          const long long a = sk[i], bb = sk[ixj];
          const bool sw = up ? (a > bb) : (a < bb);
          if (sw) { sk[i] = bb; sk[ixj] = a; const int t2 = si[i]; si[i] = si[ixj]; si[ixj] = t2; }
        }
      }
      __syncthreads();
    }
  for (int e = 0; e < 2; ++e) {
    const int t = tid + e*1024;
    sc[t] = (sk[t] != BIGK && (t == 0 || sk[t] != sk[t-1])) ? 1 : 0;
  }
  __syncthreads();
  for (int d2 = 1; d2 < NV; d2 <<= 1) {
    for (int e = 0; e < 2; ++e) { const int t = tid + e*1024; s2[t] = sc[t] + ((t >= d2) ? sc[t - d2] : 0); }
    __syncthreads();
    for (int e = 0; e < 2; ++e) { const int t = tid + e*1024; sc[t] = s2[t]; }
    __syncthreads();
  }
  for (int e = 0; e < 2; ++e) {
    const int t = tid + e*1024;
    const long long key = sk[t];
    if (key != BIGK) {
      const int g = sc[t] - 1;
      map[si[t]] = g;
      if (t == 0 || sk[t-1] != key) {
        const int w = (int)(key % Wd);
        long long r = key / Wd;
        const int h = (int)(r % H); r /= H;
        const int d = (int)(r % D);
        const int b = (int)(r / D);
        cNew[g*4+0] = b; cNew[g*4+1] = d; cNew[g*4+2] = h; cNew[g*4+3] = w;
      }
    }
  }
  if (tid == 0) *nactOut = sc[NV-1];
}

__global__ __launch_bounds__(256) void k_zero(float* __restrict__ x, int n) {
  const int idx = blockIdx.x * 256 + threadIdx.x;
  if (idx < n) x[idx] = 0.f;
}

template<int C>
__global__ __launch_bounds__(256) void k_pscatter(const float* __restrict__ src,
    float* __restrict__ dst, const int* __restrict__ map, const int* __restrict__ nactp)
{
  const int idx = blockIdx.x * 256 + threadIdx.x;
  const int i = idx / C;
  if (i >= *nactp) return;
  atomicMax((unsigned*)&dst[map[i] * C + (idx % C)], __float_as_uint(src[idx]));
}

// ---------------- final dense scatter ----------------
__global__ __launch_bounds__(256) void k_out(const float* __restrict__ f,
    const int* __restrict__ c, float* __restrict__ out, const int* __restrict__ nactp)
{
  const int idx = blockIdx.x * 256 + threadIdx.x;
  const int i = idx >> 9, ch = idx & 511;
  if (i >= *nactp) return;
  const int b = c[i*4+0], d = c[i*4+1], h = c[i*4+2], w = c[i*4+3];
  out[ (((b*512 + ch)*2 + d)*111 + h)*98 + w ] = f[idx];
}

// ---------------- host orchestration ----------------
template<int K, int CIN, int C>
static void run_stage(hipStream_t stream, int s,
    const float* Wa, const float* Ga, const float* Ba,
    const float* Wb, const float* Gb, const float* Bb,
    float* fX, float* fY, int* cX, int* cY,
    int D, int H, int W, int pd, int ph, int pw, int oD, int oH, int oW,
    long long* hk, int* hv, long long* pkey, int* pslot, int* cnt, int* map,
    int* nact, float* scale, float* shift,
    int* ocnt, int* obase, int* olist, float* P)
{
  constexpr int K3 = K*K*K;
  constexpr int CTR = K3/2;
  constexpr int CPW = C / 4;
  constexpr int NKQ = (256 / CPW) < 1 ? 1 : (256 / CPW);
  constexpr int KS1 = (CIN + 31) / 32;
  constexpr int KS2 = (C + 31) / 32;
  constexpr int NKB1 = (KS1 + NKQ - 1) / NKQ;
  constexpr int NKB2 = (KS2 + NKQ - 1) / NKQ;
  constexpr int BN   = (C < 128) ? C : 128;
  constexpr int GEMM_G = (NV / 32) * (C / BN);
  const int* na = nact + s;
  k_hclear<<<HSIZE/256, 256, 0, stream>>>(hk, ocnt);
  k_hinsert<<<NV/256, 256, 0, stream>>>(cX, hk, hv, na, D, H, W);
  k_hits<K><<<NV/4, 256, 0, stream>>>(cX, hk, hv, na, pslot, cnt, ocnt, olist, D, H, W);
  k_oscan<<<1, 512, 0, stream>>>(ocnt, obase);

  if constexpr (CIN == 1)
    k_gemm1<C><<<NV*C/256, 256, 0, stream>>>(fX, Wa + (size_t)CTR*CIN*C, fY);
  else
    k_gemm<CIN, C><<<GEMM_G, 256, 0, stream>>>(fX, Wa + (size_t)CTR*CIN*C, fY);
  k_pgemm<CIN, C><<<K3*NKB1, 256, 0, stream>>>(fX, Wa, P, ocnt, obase, olist);
  k_psum<C, KS1><<<NV*C/256, 256, 0, stream>>>(fY, P, pslot, obase, cnt, na);
  k_bnstats<C><<<C, 256, 0, stream>>>(fY, Ga, Ba, scale, shift, na);
  k_bnrelu<C><<<NV*C/256, 256, 0, stream>>>(fY, scale, shift, na);

  k_gemm<C, C><<<GEMM_G, 256, 0, stream>>>(fY, Wb + (size_t)CTR*C*C, fX);
  k_pgemm<C, C><<<K3*NKB2, 256, 0, stream>>>(fY, Wb, P, ocnt, obase, olist);
  k_psum<C, KS2><<<NV*C/256, 256, 0, stream>>>(fX, P, pslot, obase, cnt, na);
  k_bnstats<C><<<C, 256, 0, stream>>>(fX, Gb, Bb, scale, shift, na);
  k_bnrelu<C><<<NV*C/256, 256, 0, stream>>>(fX, scale, shift, na);

  k_poolkey<<<NV/256, 256, 0, stream>>>(cX, pkey, na, pd, ph, pw, oD, oH, oW);
  k_sortcompact<<<1, 1024, 0, stream>>>(pkey, cY, map, nact + s + 1, oD, oH, oW);
  k_zero<<<NV*C/256, 256, 0, stream>>>(fY, NV*C);
  k_pscatter<C><<<NV*C/256, 256, 0, stream>>>(fX, fY, map, na);
}

extern "C" void kernel_launch(void* const* d_in, const int* in_sizes, int n_in,
                              void* d_out, int out_size, void* d_ws, size_t ws_size,
                              hipStream_t stream)
{
  const float* vf    = (const float*)d_in[0];
  const int*   coors = (const int*)d_in[1];
  const float *Wl[10], *Gl[10], *Bl[10];
  for (int i = 0; i < 10; ++i) {
    Wl[i] = (const float*)d_in[3 + 3*i];
    Gl[i] = (const float*)d_in[4 + 3*i];
    Bl[i] = (const float*)d_in[5 + 3*i];
  }

  char* p = (char*)d_ws;
  auto alloc = [&](size_t bytes) { char* q = p; p += (bytes + 255) & ~(size_t)255; return q; };
  float*     fB    = (float*)    alloc((size_t)NV*512*4);
  long long* hk    = (long long*)alloc((size_t)HSIZE*8);
  long long* pkey  = (long long*)alloc((size_t)NV*8);
  int*       hv    = (int*)      alloc((size_t)HSIZE*4);
  int*       cA    = (int*)      alloc((size_t)NV*4*4);
  int*       cB    = (int*)      alloc((size_t)NV*4*4);
  int*       pslot = (int*)      alloc((size_t)NV*MAXE*4);
  int*       cnt   = (int*)      alloc((size_t)NV*4);
  int*       map   = (int*)      alloc((size_t)NV*4);
  int*       nact  = (int*)      alloc(8*4);
  float*     scale = (float*)    alloc(512*4);
  float*     shift = (float*)    alloc(512*4);
  int*       ocnt  = (int*)      alloc((size_t)K3MAX*4);
  int*       obase = (int*)      alloc((size_t)K3MAX*4);

  // scratch aliased into d_out (89 MB); all dead before the final memset
  float* fA    = (float*)d_out;                                   // 4 MB
  float* P     = (float*)((char*)d_out + (size_t)8*1024*1024);    // 40 MB budget (SLOTCAP-guarded)
  int*   olist = (int*)  ((char*)d_out + (size_t)48*1024*1024);   // 343*256*4 = 351 KB

  k_init<<<NV/256, 256, 0, stream>>>(vf, coors, cA, fA, nact);

  run_stage<7, 1, 64>  (stream, 0, Wl[0],Gl[0],Bl[0], Wl[1],Gl[1],Bl[1],
    fA, fB, cA, cB, 216, 7992, 7056, 3, 3, 3, 72, 2664, 2352,
    hk, hv, pkey, pslot, cnt, map, nact, scale, shift, ocnt, obase, olist, P);
  run_stage<7, 64, 128>(stream, 1, Wl[2],Gl[2],Bl[2], Wl[3],Gl[3],Bl[3],
    fB, fA, cB, cA, 72, 2664, 2352, 3, 3, 3, 24, 888, 784,
    hk, hv, pkey, pslot, cnt, map, nact, scale, shift, ocnt, obase, olist, P);
  run_stage<5, 128, 256>(stream, 2, Wl[4],Gl[4],Bl[4], Wl[5],Gl[5],Bl[5],
    fA, fB, cA, cB, 24, 888, 784, 3, 2, 2, 8, 444, 392,
    hk, hv, pkey, pslot, cnt, map, nact, scale, shift, ocnt, obase, olist, P);
  run_stage<3, 256, 384>(stream, 3, Wl[6],Gl[6],Bl[6], Wl[7],Gl[7],Bl[7],
    fB, fA, cB, cA, 8, 444, 392, 2, 2, 2, 4, 222, 196,
    hk, hv, pkey, pslot, cnt, map, nact, scale, shift, ocnt, obase, olist, P);
  run_stage<3, 384, 512>(stream, 4, Wl[8],Gl[8],Bl[8], Wl[9],Gl[9],Bl[9],
    fA, fB, cA, cB, 4, 222, 196, 2, 2, 2, 2, 111, 98,
    hk, hv, pkey, pslot, cnt, map, nact, scale, shift, ocnt, obase, olist, P);

  hipMemsetAsync(d_out, 0, (size_t)out_size * sizeof(float), stream);
  k_out<<<NV*512/256, 256, 0, stream>>>(fB, cB, (float*)d_out, nact + 5);
}